// Round 6
// baseline (72865.228 us; speedup 1.0000x reference)
//
#include <hip/hip_runtime.h>
#include <stdint.h>

// BiRNN: 2-layer BiLSTM (U=256) + heads. B=32, T=2048, F=64.
// R6: aliasing fix — h1 gets its own (bf16) buffer; h0 (f32) is read-only
// during layer 1. Fast kernels restored (validated ≡ naive by R4/R5 bit-match).
//  - GEMM: in-kernel bf16 hi/lo split of f32 operands, 3-term MFMA (~f32 acc).
//  - Recurrence: 4 WGs per (dir,batch) chain; U slice register-resident f32;
//    per-step h exchange via agent-scope atomics + release/acquire flags.
//  - Sequence chunked (adaptive S) so xW scratch fits ws_size.

#define T_SEQ 2048
#define BATCH 32
#define NROWS 65536   // B*T
#define NG 1024       // 4*U

typedef __attribute__((ext_vector_type(8))) short short8;
typedef __attribute__((ext_vector_type(4))) float f32x4;
typedef __attribute__((ext_vector_type(2))) float f32x2;

__device__ __forceinline__ ushort f32_to_bf16(float f) {
    uint32_t u = __float_as_uint(f);
    u = u + 0x7FFFu + ((u >> 16) & 1u);   // RNE
    return (ushort)(u >> 16);
}
__device__ __forceinline__ float bf16_to_f32(ushort h) {
    return __uint_as_float(((uint32_t)h) << 16);
}
__device__ __forceinline__ uint64_t split_pack4(f32x4 v, uint64_t& lo64) {
    ushort h0 = f32_to_bf16(v[0]), h1 = f32_to_bf16(v[1]);
    ushort h2 = f32_to_bf16(v[2]), h3 = f32_to_bf16(v[3]);
    ushort l0 = f32_to_bf16(v[0] - bf16_to_f32(h0));
    ushort l1 = f32_to_bf16(v[1] - bf16_to_f32(h1));
    ushort l2 = f32_to_bf16(v[2] - bf16_to_f32(h2));
    ushort l3 = f32_to_bf16(v[3] - bf16_to_f32(h3));
    lo64 = (uint64_t)l0 | ((uint64_t)l1 << 16) | ((uint64_t)l2 << 32) | ((uint64_t)l3 << 48);
    return (uint64_t)h0 | ((uint64_t)h1 << 16) | ((uint64_t)h2 << 32) | ((uint64_t)h3 << 48);
}

__global__ void init_flags_kernel(int* __restrict__ flags) {
    int i = blockIdx.x * 256 + threadIdx.x;
    if (i < 512) flags[i] = 0;
}

// Chunked split-GEMM: Cc[b*S+loc][:] = A[row_g][:] @ Bw + bias (all f32 I/O).
// A f32 [NROWS][K]; Bw f32 [K][NG]. In-kernel bf16 hi/lo split, 3-term MFMA.
// row_g = b*T + (dir ? T-1-cb-loc : cb+loc).
__global__ __launch_bounds__(256) void gemm_split_kernel(
    const float* __restrict__ A, int K,
    const float* __restrict__ Bw, const float* __restrict__ bias,
    float* __restrict__ Cc, int cb, int lsS, int dir)
{
    __shared__ __align__(16) ushort Ash[128 * 36];
    __shared__ __align__(16) ushort Asl[128 * 36];
    __shared__ __align__(16) ushort Bsh[128 * 36];
    __shared__ __align__(16) ushort Bsl[128 * 36];
    const int Smask = (1 << lsS) - 1;
    int t = threadIdx.x;
    int n0 = blockIdx.x * 128;
    int m0 = blockIdx.y * 128;
    int lane = t & 63, wv = t >> 6;
    int wr = wv >> 1, wc = wv & 1;
    int fr = lane & 15, fq = lane >> 4;

    f32x4 acc[4][4];
#pragma unroll
    for (int i = 0; i < 4; i++)
#pragma unroll
        for (int j = 0; j < 4; j++) acc[i][j] = (f32x4)(0.0f);

    int arow = t >> 1, ahalf = t & 1;
    int bc = t & 127, bkh = t >> 7;

    int loc_all = m0 + arow;
    int b = loc_all >> lsS;
    int loc = loc_all & Smask;
    int row_g = b * T_SEQ + (dir ? (T_SEQ - 1 - cb - loc) : (cb + loc));

    for (int k0 = 0; k0 < K; k0 += 32) {
        {   // stage A tile 128x32: 16 f32 per thread, split to hi/lo
            const float* s = A + (size_t)row_g * K + k0 + ahalf * 16;
            uint64_t* dh = (uint64_t*)&Ash[arow * 36 + ahalf * 16];
            uint64_t* dl = (uint64_t*)&Asl[arow * 36 + ahalf * 16];
#pragma unroll
            for (int g = 0; g < 4; g++) {
                f32x4 v = ((const f32x4*)s)[g];
                uint64_t lo64;
                uint64_t hi64 = split_pack4(v, lo64);
                dh[g] = hi64; dl[g] = lo64;
            }
        }
        {   // stage B tile 32x128 transposed -> [c][k], split to hi/lo
            float bv[16];
#pragma unroll
            for (int i = 0; i < 16; i++)
                bv[i] = Bw[(size_t)(k0 + bkh * 16 + i) * NG + n0 + bc];
            uint64_t* dh = (uint64_t*)&Bsh[bc * 36 + bkh * 16];
            uint64_t* dl = (uint64_t*)&Bsl[bc * 36 + bkh * 16];
#pragma unroll
            for (int g = 0; g < 4; g++) {
                f32x4 v = { bv[4 * g], bv[4 * g + 1], bv[4 * g + 2], bv[4 * g + 3] };
                uint64_t lo64;
                uint64_t hi64 = split_pack4(v, lo64);
                dh[g] = hi64; dl[g] = lo64;
            }
        }
        __syncthreads();
        union FU { uint64_t u[2]; short8 v; };
        FU bh[4], bl[4];
#pragma unroll
        for (int n = 0; n < 4; n++) {
            int boff = (wc * 64 + n * 16 + fr) * 36 + fq * 8;
            bh[n].u[0] = ((const uint64_t*)&Bsh[boff])[0];
            bh[n].u[1] = ((const uint64_t*)&Bsh[boff])[1];
            bl[n].u[0] = ((const uint64_t*)&Bsl[boff])[0];
            bl[n].u[1] = ((const uint64_t*)&Bsl[boff])[1];
        }
#pragma unroll
        for (int m = 0; m < 4; m++) {
            int aoff = (wr * 64 + m * 16 + fr) * 36 + fq * 8;
            FU ah, al;
            ah.u[0] = ((const uint64_t*)&Ash[aoff])[0];
            ah.u[1] = ((const uint64_t*)&Ash[aoff])[1];
            al.u[0] = ((const uint64_t*)&Asl[aoff])[0];
            al.u[1] = ((const uint64_t*)&Asl[aoff])[1];
#pragma unroll
            for (int n = 0; n < 4; n++) {
                acc[m][n] = __builtin_amdgcn_mfma_f32_16x16x32_bf16(ah.v, bh[n].v, acc[m][n], 0, 0, 0);
                acc[m][n] = __builtin_amdgcn_mfma_f32_16x16x32_bf16(ah.v, bl[n].v, acc[m][n], 0, 0, 0);
                acc[m][n] = __builtin_amdgcn_mfma_f32_16x16x32_bf16(al.v, bh[n].v, acc[m][n], 0, 0, 0);
            }
        }
        __syncthreads();
    }
    // D layout: col=lane&15, row=(lane>>4)*4+i
#pragma unroll
    for (int m = 0; m < 4; m++)
#pragma unroll
        for (int n = 0; n < 4; n++) {
            int gcol = n0 + wc * 64 + n * 16 + fr;
            float bvv = bias[gcol];
#pragma unroll
            for (int i = 0; i < 4; i++) {
                int crow = m0 + wr * 64 + m * 16 + fq * 4 + i;
                Cc[(size_t)crow * NG + gcol] = acc[m][n][i] + bvv;
            }
        }
}

// One chunk of S steps for 2 LSTMs (fwd+bwd). 256 WGs: chain = wg>>2, w = wg&3.
// Writes h to houtF (f32) if non-null, else houtB (bf16).
__global__ __launch_bounds__(512) void lstm_kernel(
    const float* __restrict__ Uf, const float* __restrict__ Ub,
    const float* __restrict__ xWcf, const float* __restrict__ xWcb,  // [B][S][NG] f32
    const int* __restrict__ mask,
    float* __restrict__ houtF,             // [NROWS][512] f32, +dir*256 (or null)
    ushort* __restrict__ houtB,            // [NROWS][512] bf16, +dir*256 (or null)
    float* __restrict__ hx,                // [64][2][256] parity by global step
    float* __restrict__ cstate,            // [64][256]
    int* __restrict__ flags,               // [64][4], monotone global step
    int cb, int S)
{
    int wg = blockIdx.x;
    int chain = wg >> 2;
    int w = wg & 3;
    int dir = chain >> 5;
    int b = chain & 31;
    const float* U = dir ? Ub : Uf;
    const float* xWc = dir ? xWcb : xWcf;

    int t = threadIdx.x;
    __shared__ __align__(16) float hbuf[256];
    __shared__ __align__(16) float pbuf[4 * 256];
    __shared__ __align__(16) float zbuf[256];

    int kchunk = t >> 7;
    int cg = t & 127;
    int q = cg >> 5;
    int jj0 = 2 * (cg & 31);
    int col0 = q * 256 + w * 64 + jj0;

    // U slice in registers: 64 k x 2 cols = 128 VGPRs
    f32x2 Ur[64];
    {
        const float* Up = U + (size_t)(kchunk * 64) * NG + col0;
#pragma unroll
        for (int i = 0; i < 64; i++) Ur[i] = *(const f32x2*)(Up + (size_t)i * NG);
    }
    float* hxc = hx + chain * 512;
    int* flg = flags + chain * 4;
    int gj = w * 64 + (t & 63);
    if (t < 256) hbuf[t] = (cb == 0) ? 0.0f : hxc[((cb - 1) & 1) * 256 + t];
    float creg = 0.0f, hreg = 0.0f;
    if (t < 64 && cb != 0) {
        creg = cstate[chain * 256 + gj];
        hreg = hxc[((cb - 1) & 1) * 256 + gj];
    }
    int colS = (t < 256) ? ((t >> 6) * 256 + w * 64 + (t & 63)) : 0;
    int owner = t >> 6;
    __syncthreads();

    for (int nl = 0; nl < S; nl++) {
        int n = cb + nl;
        int tp = dir ? (T_SEQ - 1 - n) : n;
        size_t row_g = (size_t)b * T_SEQ + tp;
        float xwv = 0.0f;
        if (t < 256) xwv = xWc[((size_t)b * S + nl) * NG + colS];
        int mval = mask[row_g];
        if (n > 0 && t < 256 && owner != w) {
            while (__hip_atomic_load(&flg[owner], __ATOMIC_ACQUIRE, __HIP_MEMORY_SCOPE_AGENT) < n)
                __builtin_amdgcn_s_sleep(1);
            hbuf[t] = __hip_atomic_load(&hxc[((n - 1) & 1) * 256 + t], __ATOMIC_RELAXED, __HIP_MEMORY_SCOPE_AGENT);
        }
        __syncthreads();
        // partial dot: 2 cols x 64 k, exact f32 FMA
        float a0 = 0.0f, a1 = 0.0f;
        {
            const float* hb = &hbuf[kchunk * 64];
#pragma unroll
            for (int i = 0; i < 16; i++) {
                f32x4 h4 = *(const f32x4*)(hb + 4 * i);
#pragma unroll
                for (int j2 = 0; j2 < 4; j2++) {
                    a0 += h4[j2] * Ur[4 * i + j2][0];
                    a1 += h4[j2] * Ur[4 * i + j2][1];
                }
            }
        }
        {
            f32x2 pv = {a0, a1};
            *(f32x2*)&pbuf[kchunk * 256 + 2 * cg] = pv;
        }
        __syncthreads();
        if (t < 256)
            zbuf[t] = xwv + pbuf[t] + pbuf[256 + t] + pbuf[512 + t] + pbuf[768 + t];
        __syncthreads();
        if (t < 64) {
            float zi = zbuf[t], zf = zbuf[64 + t], zg = zbuf[128 + t], zo = zbuf[192 + t];
            float ig = 1.0f / (1.0f + expf(-zi));
            float fg = 1.0f / (1.0f + expf(-zf));
            float gg = tanhf(zg);
            float og = 1.0f / (1.0f + expf(-zo));
            float cn = fg * creg + ig * gg;
            float hn = og * tanhf(cn);
            if (mval == 1) { hn = hreg; cn = creg; }   // x_mask==1 -> hold
            creg = cn; hreg = hn;
            hbuf[gj] = hn;
            size_t oidx = row_g * 512 + dir * 256 + gj;
            if (houtF) houtF[oidx] = hn;
            else       houtB[oidx] = f32_to_bf16(hn);
            __hip_atomic_store(&hxc[(n & 1) * 256 + gj], hn, __ATOMIC_RELAXED, __HIP_MEMORY_SCOPE_AGENT);
            if (t == 0)
                __hip_atomic_store(&flg[w], n + 1, __ATOMIC_RELEASE, __HIP_MEMORY_SCOPE_AGENT);
        }
    }
    if (t < 64) cstate[chain * 256 + gj] = creg;
}

struct HP { const float* W; const float* bs; int nc; int lc; size_t off; };
__device__ __forceinline__ HP resolve_head(int j,
    const float* Wp, const float* bp, const float* Wbu, const float* bbu,
    const float* W3, const float* b3, const float* W8, const float* b8,
    const float* Wa, const float* ba, const float* Wpp, const float* bpp)
{
    HP h;
    if (j < 2)       { h.W = Wp;  h.bs = bp;  h.nc = 2; h.lc = j;      h.off = 0; }
    else if (j < 4)  { h.W = Wbu; h.bs = bbu; h.nc = 2; h.lc = j - 2;  h.off = (size_t)NROWS * 2; }
    else if (j < 7)  { h.W = W3;  h.bs = b3;  h.nc = 3; h.lc = j - 4;  h.off = (size_t)NROWS * 4; }
    else if (j < 15) { h.W = W8;  h.bs = b8;  h.nc = 8; h.lc = j - 7;  h.off = (size_t)NROWS * 7; }
    else if (j < 16) { h.W = Wa;  h.bs = ba;  h.nc = 1; h.lc = 0;      h.off = (size_t)NROWS * 15; }
    else             { h.W = Wpp; h.bs = bpp; h.nc = 4; h.lc = j - 16; h.off = (size_t)NROWS * 16; }
    return h;
}

__global__ __launch_bounds__(256) void heads_kernel(
    const ushort* __restrict__ h1,   // [NROWS][512] bf16
    const float* __restrict__ Wp, const float* __restrict__ bp,
    const float* __restrict__ Wbu, const float* __restrict__ bbu,
    const float* __restrict__ W3, const float* __restrict__ b3,
    const float* __restrict__ W8, const float* __restrict__ b8,
    const float* __restrict__ Wa, const float* __restrict__ ba,
    const float* __restrict__ Wpp, const float* __restrict__ bpp,
    float* __restrict__ out)
{
    int idx = blockIdx.x * 256 + threadIdx.x;
    if (idx >= NROWS * 10) return;
    int r = idx / 10;
    int pair = idx - r * 10;
    int j0 = 2 * pair;
    HP p0 = resolve_head(j0, Wp, bp, Wbu, bbu, W3, b3, W8, b8, Wa, ba, Wpp, bpp);
    HP p1 = resolve_head(j0 + 1, Wp, bp, Wbu, bbu, W3, b3, W8, b8, Wa, ba, Wpp, bpp);
    const ushort* hr = h1 + (size_t)r * 512;
    float s0 = 0.0f, s1 = 0.0f;
    for (int k = 0; k < 512; k += 8) {
        union { uint4 u4; ushort us[8]; } hu;
        hu.u4 = *(const uint4*)(hr + k);
#pragma unroll
        for (int u = 0; u < 8; u++) {
            float hv = fmaxf(bf16_to_f32(hu.us[u]), 0.0f);   // relu
            s0 += hv * p0.W[(k + u) * p0.nc + p0.lc];
            s1 += hv * p1.W[(k + u) * p1.nc + p1.lc];
        }
    }
    s0 += p0.bs[p0.lc];
    s1 += p1.bs[p1.lc];
    if (pair == 0) {   // ppi softmax over 2 logits
        float mx = fmaxf(s0, s1);
        float e0 = expf(s0 - mx), e1 = expf(s1 - mx);
        float inv = 1.0f / (e0 + e1);
        out[(size_t)r * 2]     = e0 * inv;
        out[(size_t)r * 2 + 1] = e1 * inv;
    } else {
        out[p0.off + (size_t)r * p0.nc + p0.lc] = s0;
        out[p1.off + (size_t)r * p1.nc + p1.lc] = s1;
    }
}

extern "C" void kernel_launch(void* const* d_in, const int* in_sizes, int n_in,
                              void* d_out, int out_size, void* d_ws, size_t ws_size,
                              hipStream_t stream) {
    const float* x    = (const float*)d_in[0];
    const int* xmask  = (const int*)d_in[1];
    const float* Wf0  = (const float*)d_in[3];
    const float* Uf0  = (const float*)d_in[4];
    const float* bf0  = (const float*)d_in[5];
    const float* Wb0  = (const float*)d_in[6];
    const float* Ub0  = (const float*)d_in[7];
    const float* bb0  = (const float*)d_in[8];
    const float* Wf1  = (const float*)d_in[9];
    const float* Uf1  = (const float*)d_in[10];
    const float* bf1  = (const float*)d_in[11];
    const float* Wb1  = (const float*)d_in[12];
    const float* Ub1  = (const float*)d_in[13];
    const float* bb1  = (const float*)d_in[14];
    const float* Wp   = (const float*)d_in[15]; const float* bp  = (const float*)d_in[16];
    const float* Wbu  = (const float*)d_in[17]; const float* bbu = (const float*)d_in[18];
    const float* W3   = (const float*)d_in[19]; const float* b3  = (const float*)d_in[20];
    const float* W8   = (const float*)d_in[21]; const float* b8  = (const float*)d_in[22];
    const float* Wa   = (const float*)d_in[23]; const float* ba  = (const float*)d_in[24];
    const float* Wpp  = (const float*)d_in[25]; const float* bpp = (const float*)d_in[26];
    float* out = (float*)d_out;

    char* ws = (char*)d_ws;
    size_t off = 0;
    auto take = [&](size_t bytes) -> void* {
        void* p = ws + off;
        off += (bytes + 255) & ~(size_t)255;
        return p;
    };
    int*    flags  = (int*)take(512 * 4);
    float*  hx     = (float*)take((size_t)64 * 2 * 256 * 4);
    float*  cstate = (float*)take((size_t)64 * 256 * 4);
    float*  h0F    = (float*)take((size_t)NROWS * 512 * 4);    // 134.2 MB, layer-0 h (f32)
    ushort* h1B    = (ushort*)take((size_t)NROWS * 512 * 2);   // 67.1 MB, layer-1 h (bf16)
    size_t fixed = off;

    // adaptive chunk: xW f32 chunk buffers cost S*262144 bytes (both dirs)
    int S = 8, lsS = 3;
    for (int cand = 11; cand >= 3; cand--) {
        if (fixed + (((size_t)1 << cand) * 262144) + 4096 <= ws_size) { S = 1 << cand; lsS = cand; break; }
    }
    float* xWcf = (float*)take((size_t)BATCH * S * NG * 4);
    float* xWcb = (float*)take((size_t)BATCH * S * NG * 4);
    int NC = T_SEQ / S;
    (void)in_sizes; (void)n_in; (void)out_size;

    init_flags_kernel<<<2, 256, 0, stream>>>(flags);

    dim3 ggrid(NG / 128, (BATCH * S) / 128);
    // layer 0: A = x (f32, K=64), writes h0F (f32)
    for (int c = 0; c < NC; c++) {
        int cb = c * S;
        gemm_split_kernel<<<ggrid, 256, 0, stream>>>(x, 64, Wf0, bf0, xWcf, cb, lsS, 0);
        gemm_split_kernel<<<ggrid, 256, 0, stream>>>(x, 64, Wb0, bb0, xWcb, cb, lsS, 1);
        lstm_kernel<<<256, 512, 0, stream>>>(Uf0, Ub0, xWcf, xWcb, xmask, h0F, nullptr,
                                             hx, cstate, flags, cb, S);
    }
    // layer 1: A = h0F (f32, K=512, READ-ONLY now), writes h1B (bf16) — no aliasing
    for (int c = 0; c < NC; c++) {
        int cb = c * S;
        gemm_split_kernel<<<ggrid, 256, 0, stream>>>(h0F, 512, Wf1, bf1, xWcf, cb, lsS, 0);
        gemm_split_kernel<<<ggrid, 256, 0, stream>>>(h0F, 512, Wb1, bb1, xWcb, cb, lsS, 1);
        lstm_kernel<<<256, 512, 0, stream>>>(Uf1, Ub1, xWcf, xWcb, xmask, nullptr, h1B,
                                             hx, cstate, flags + 256, cb, S);
    }

    heads_kernel<<<(NROWS * 10 + 255) / 256, 256, 0, stream>>>(
        h1B, Wp, bp, Wbu, bbu, W3, b3, W8, b8, Wa, ba, Wpp, bpp, out);
}

// Round 7
// 47889.709 us; speedup vs baseline: 1.5215x; 1.5215x over previous
//
#include <hip/hip_runtime.h>
#include <stdint.h>

// BiRNN: 2-layer BiLSTM (U=256) + heads. B=32, T=2048, F=64.
// R7 (perf): (1) __launch_bounds__(512,2) so the 128-VGPR U slice is truly
// register-resident (R6 ran at VGPR=84 => demoted); (2) relaxed spin polls with
// a single acquire confirm (R6 paid agent-scope cache maintenance per poll);
// (3) fused z-assembly into cell threads (2 barriers/step instead of 3).
// Numerics identical to the R6 configuration that passed (absmax 3.9e-3).

#define T_SEQ 2048
#define BATCH 32
#define NROWS 65536   // B*T
#define NG 1024       // 4*U

typedef __attribute__((ext_vector_type(8))) short short8;
typedef __attribute__((ext_vector_type(4))) float f32x4;
typedef __attribute__((ext_vector_type(2))) float f32x2;

__device__ __forceinline__ ushort f32_to_bf16(float f) {
    uint32_t u = __float_as_uint(f);
    u = u + 0x7FFFu + ((u >> 16) & 1u);   // RNE
    return (ushort)(u >> 16);
}
__device__ __forceinline__ float bf16_to_f32(ushort h) {
    return __uint_as_float(((uint32_t)h) << 16);
}
__device__ __forceinline__ uint64_t split_pack4(f32x4 v, uint64_t& lo64) {
    ushort h0 = f32_to_bf16(v[0]), h1 = f32_to_bf16(v[1]);
    ushort h2 = f32_to_bf16(v[2]), h3 = f32_to_bf16(v[3]);
    ushort l0 = f32_to_bf16(v[0] - bf16_to_f32(h0));
    ushort l1 = f32_to_bf16(v[1] - bf16_to_f32(h1));
    ushort l2 = f32_to_bf16(v[2] - bf16_to_f32(h2));
    ushort l3 = f32_to_bf16(v[3] - bf16_to_f32(h3));
    lo64 = (uint64_t)l0 | ((uint64_t)l1 << 16) | ((uint64_t)l2 << 32) | ((uint64_t)l3 << 48);
    return (uint64_t)h0 | ((uint64_t)h1 << 16) | ((uint64_t)h2 << 32) | ((uint64_t)h3 << 48);
}

__global__ void init_flags_kernel(int* __restrict__ flags) {
    int i = blockIdx.x * 256 + threadIdx.x;
    if (i < 512) flags[i] = 0;
}

// Chunked split-GEMM: Cc[b*S+loc][:] = A[row_g][:] @ Bw + bias (all f32 I/O).
__global__ __launch_bounds__(256) void gemm_split_kernel(
    const float* __restrict__ A, int K,
    const float* __restrict__ Bw, const float* __restrict__ bias,
    float* __restrict__ Cc, int cb, int lsS, int dir)
{
    __shared__ __align__(16) ushort Ash[128 * 36];
    __shared__ __align__(16) ushort Asl[128 * 36];
    __shared__ __align__(16) ushort Bsh[128 * 36];
    __shared__ __align__(16) ushort Bsl[128 * 36];
    const int Smask = (1 << lsS) - 1;
    int t = threadIdx.x;
    int n0 = blockIdx.x * 128;
    int m0 = blockIdx.y * 128;
    int lane = t & 63, wv = t >> 6;
    int wr = wv >> 1, wc = wv & 1;
    int fr = lane & 15, fq = lane >> 4;

    f32x4 acc[4][4];
#pragma unroll
    for (int i = 0; i < 4; i++)
#pragma unroll
        for (int j = 0; j < 4; j++) acc[i][j] = (f32x4)(0.0f);

    int arow = t >> 1, ahalf = t & 1;
    int bc = t & 127, bkh = t >> 7;

    int loc_all = m0 + arow;
    int b = loc_all >> lsS;
    int loc = loc_all & Smask;
    int row_g = b * T_SEQ + (dir ? (T_SEQ - 1 - cb - loc) : (cb + loc));

    for (int k0 = 0; k0 < K; k0 += 32) {
        {   // stage A tile 128x32: 16 f32 per thread, split to hi/lo
            const float* s = A + (size_t)row_g * K + k0 + ahalf * 16;
            uint64_t* dh = (uint64_t*)&Ash[arow * 36 + ahalf * 16];
            uint64_t* dl = (uint64_t*)&Asl[arow * 36 + ahalf * 16];
#pragma unroll
            for (int g = 0; g < 4; g++) {
                f32x4 v = ((const f32x4*)s)[g];
                uint64_t lo64;
                uint64_t hi64 = split_pack4(v, lo64);
                dh[g] = hi64; dl[g] = lo64;
            }
        }
        {   // stage B tile 32x128 transposed -> [c][k], split to hi/lo
            float bv[16];
#pragma unroll
            for (int i = 0; i < 16; i++)
                bv[i] = Bw[(size_t)(k0 + bkh * 16 + i) * NG + n0 + bc];
            uint64_t* dh = (uint64_t*)&Bsh[bc * 36 + bkh * 16];
            uint64_t* dl = (uint64_t*)&Bsl[bc * 36 + bkh * 16];
#pragma unroll
            for (int g = 0; g < 4; g++) {
                f32x4 v = { bv[4 * g], bv[4 * g + 1], bv[4 * g + 2], bv[4 * g + 3] };
                uint64_t lo64;
                uint64_t hi64 = split_pack4(v, lo64);
                dh[g] = hi64; dl[g] = lo64;
            }
        }
        __syncthreads();
        union FU { uint64_t u[2]; short8 v; };
        FU bh[4], bl[4];
#pragma unroll
        for (int n = 0; n < 4; n++) {
            int boff = (wc * 64 + n * 16 + fr) * 36 + fq * 8;
            bh[n].u[0] = ((const uint64_t*)&Bsh[boff])[0];
            bh[n].u[1] = ((const uint64_t*)&Bsh[boff])[1];
            bl[n].u[0] = ((const uint64_t*)&Bsl[boff])[0];
            bl[n].u[1] = ((const uint64_t*)&Bsl[boff])[1];
        }
#pragma unroll
        for (int m = 0; m < 4; m++) {
            int aoff = (wr * 64 + m * 16 + fr) * 36 + fq * 8;
            FU ah, al;
            ah.u[0] = ((const uint64_t*)&Ash[aoff])[0];
            ah.u[1] = ((const uint64_t*)&Ash[aoff])[1];
            al.u[0] = ((const uint64_t*)&Asl[aoff])[0];
            al.u[1] = ((const uint64_t*)&Asl[aoff])[1];
#pragma unroll
            for (int n = 0; n < 4; n++) {
                acc[m][n] = __builtin_amdgcn_mfma_f32_16x16x32_bf16(ah.v, bh[n].v, acc[m][n], 0, 0, 0);
                acc[m][n] = __builtin_amdgcn_mfma_f32_16x16x32_bf16(ah.v, bl[n].v, acc[m][n], 0, 0, 0);
                acc[m][n] = __builtin_amdgcn_mfma_f32_16x16x32_bf16(al.v, bh[n].v, acc[m][n], 0, 0, 0);
            }
        }
        __syncthreads();
    }
#pragma unroll
    for (int m = 0; m < 4; m++)
#pragma unroll
        for (int n = 0; n < 4; n++) {
            int gcol = n0 + wc * 64 + n * 16 + fr;
            float bvv = bias[gcol];
#pragma unroll
            for (int i = 0; i < 4; i++) {
                int crow = m0 + wr * 64 + m * 16 + fq * 4 + i;
                Cc[(size_t)crow * NG + gcol] = acc[m][n][i] + bvv;
            }
        }
}

// One chunk of S steps for 2 LSTMs (fwd+bwd). 256 WGs: chain = wg>>2, w = wg&3.
// __launch_bounds__(512,2): 1 block/CU, 256-VGPR budget -> Ur stays in VGPRs.
__global__ __launch_bounds__(512, 2) void lstm_kernel(
    const float* __restrict__ Uf, const float* __restrict__ Ub,
    const float* __restrict__ xWcf, const float* __restrict__ xWcb,  // [B][S][NG] f32
    const int* __restrict__ mask,
    float* __restrict__ houtF,             // [NROWS][512] f32, +dir*256 (or null)
    ushort* __restrict__ houtB,            // [NROWS][512] bf16, +dir*256 (or null)
    float* __restrict__ hx,                // [64][2][256] parity by global step
    float* __restrict__ cstate,            // [64][256]
    int* __restrict__ flags,               // [64][4], monotone global step
    int cb, int S)
{
    int wg = blockIdx.x;
    int chain = wg >> 2;
    int w = wg & 3;
    int dir = chain >> 5;
    int b = chain & 31;
    const float* U = dir ? Ub : Uf;
    const float* xWc = dir ? xWcb : xWcf;

    int t = threadIdx.x;
    __shared__ __align__(16) float hbuf[256];
    __shared__ __align__(16) float pbuf[4 * 256];

    int kchunk = t >> 7;
    int cg = t & 127;
    int q = cg >> 5;
    int jj0 = 2 * (cg & 31);
    int col0 = q * 256 + w * 64 + jj0;

    // U slice in registers: 64 k x 2 cols = 128 VGPRs
    f32x2 Ur[64];
    {
        const float* Up = U + (size_t)(kchunk * 64) * NG + col0;
#pragma unroll
        for (int i = 0; i < 64; i++) Ur[i] = *(const f32x2*)(Up + (size_t)i * NG);
    }
    float* hxc = hx + chain * 512;
    int* flg = flags + chain * 4;
    int j = t & 63;
    int gj = w * 64 + j;
    if (t < 256) hbuf[t] = (cb == 0) ? 0.0f : hxc[((cb - 1) & 1) * 256 + t];
    float creg = 0.0f, hreg = 0.0f;
    if (t < 64 && cb != 0) {
        creg = cstate[chain * 256 + gj];
        hreg = hxc[((cb - 1) & 1) * 256 + gj];
    }
    int owner = t >> 6;
    __syncthreads();

    for (int nl = 0; nl < S; nl++) {
        int n = cb + nl;
        int tp = dir ? (T_SEQ - 1 - n) : n;
        size_t row_g = (size_t)b * T_SEQ + tp;
        // cell threads issue their 4 xW loads + mask early (hidden under spin)
        float xw0 = 0.f, xw1 = 0.f, xw2 = 0.f, xw3 = 0.f;
        int mval = 0;
        if (t < 64) {
            const float* xr = xWc + ((size_t)b * S + nl) * NG;
            xw0 = xr[gj];
            xw1 = xr[256 + gj];
            xw2 = xr[512 + gj];
            xw3 = xr[768 + gj];
            mval = mask[row_g];
        }
        // gather foreign h slices (h_{n-1}): relaxed polls, one acquire confirm
        if (n > 0 && t < 256 && owner != w) {
            while (__hip_atomic_load(&flg[owner], __ATOMIC_RELAXED, __HIP_MEMORY_SCOPE_AGENT) < n)
                __builtin_amdgcn_s_sleep(2);
            (void)__hip_atomic_load(&flg[owner], __ATOMIC_ACQUIRE, __HIP_MEMORY_SCOPE_AGENT);
            hbuf[t] = __hip_atomic_load(&hxc[((n - 1) & 1) * 256 + t], __ATOMIC_RELAXED, __HIP_MEMORY_SCOPE_AGENT);
        }
        __syncthreads();   // (C)
        // partial dot: 2 cols x 64 k, exact f32 FMA, U in registers
        float a0 = 0.0f, a1 = 0.0f;
        {
            const float* hb = &hbuf[kchunk * 64];
#pragma unroll
            for (int i = 0; i < 16; i++) {
                f32x4 h4 = *(const f32x4*)(hb + 4 * i);
#pragma unroll
                for (int j2 = 0; j2 < 4; j2++) {
                    a0 += h4[j2] * Ur[4 * i + j2][0];
                    a1 += h4[j2] * Ur[4 * i + j2][1];
                }
            }
        }
        {
            f32x2 pv = {a0, a1};
            *(f32x2*)&pbuf[kchunk * 256 + 2 * cg] = pv;
        }
        __syncthreads();   // (E)
        if (t < 64) {
            float zi = xw0 + pbuf[j]       + pbuf[256 + j]       + pbuf[512 + j]       + pbuf[768 + j];
            float zf = xw1 + pbuf[64 + j]  + pbuf[256 + 64 + j]  + pbuf[512 + 64 + j]  + pbuf[768 + 64 + j];
            float zg = xw2 + pbuf[128 + j] + pbuf[256 + 128 + j] + pbuf[512 + 128 + j] + pbuf[768 + 128 + j];
            float zo = xw3 + pbuf[192 + j] + pbuf[256 + 192 + j] + pbuf[512 + 192 + j] + pbuf[768 + 192 + j];
            float ig = 1.0f / (1.0f + expf(-zi));
            float fg = 1.0f / (1.0f + expf(-zf));
            float gg = tanhf(zg);
            float og = 1.0f / (1.0f + expf(-zo));
            float cn = fg * creg + ig * gg;
            float hn = og * tanhf(cn);
            if (mval == 1) { hn = hreg; cn = creg; }   // x_mask==1 -> hold
            creg = cn; hreg = hn;
            hbuf[gj] = hn;
            size_t oidx = row_g * 512 + dir * 256 + gj;
            if (houtF) houtF[oidx] = hn;
            else       houtB[oidx] = f32_to_bf16(hn);
            __hip_atomic_store(&hxc[(n & 1) * 256 + gj], hn, __ATOMIC_RELAXED, __HIP_MEMORY_SCOPE_AGENT);
            if (t == 0)
                __hip_atomic_store(&flg[w], n + 1, __ATOMIC_RELEASE, __HIP_MEMORY_SCOPE_AGENT);
        }
    }
    if (t < 64) cstate[chain * 256 + gj] = creg;
}

struct HP { const float* W; const float* bs; int nc; int lc; size_t off; };
__device__ __forceinline__ HP resolve_head(int j,
    const float* Wp, const float* bp, const float* Wbu, const float* bbu,
    const float* W3, const float* b3, const float* W8, const float* b8,
    const float* Wa, const float* ba, const float* Wpp, const float* bpp)
{
    HP h;
    if (j < 2)       { h.W = Wp;  h.bs = bp;  h.nc = 2; h.lc = j;      h.off = 0; }
    else if (j < 4)  { h.W = Wbu; h.bs = bbu; h.nc = 2; h.lc = j - 2;  h.off = (size_t)NROWS * 2; }
    else if (j < 7)  { h.W = W3;  h.bs = b3;  h.nc = 3; h.lc = j - 4;  h.off = (size_t)NROWS * 4; }
    else if (j < 15) { h.W = W8;  h.bs = b8;  h.nc = 8; h.lc = j - 7;  h.off = (size_t)NROWS * 7; }
    else if (j < 16) { h.W = Wa;  h.bs = ba;  h.nc = 1; h.lc = 0;      h.off = (size_t)NROWS * 15; }
    else             { h.W = Wpp; h.bs = bpp; h.nc = 4; h.lc = j - 16; h.off = (size_t)NROWS * 16; }
    return h;
}

__global__ __launch_bounds__(256) void heads_kernel(
    const ushort* __restrict__ h1,   // [NROWS][512] bf16
    const float* __restrict__ Wp, const float* __restrict__ bp,
    const float* __restrict__ Wbu, const float* __restrict__ bbu,
    const float* __restrict__ W3, const float* __restrict__ b3,
    const float* __restrict__ W8, const float* __restrict__ b8,
    const float* __restrict__ Wa, const float* __restrict__ ba,
    const float* __restrict__ Wpp, const float* __restrict__ bpp,
    float* __restrict__ out)
{
    int idx = blockIdx.x * 256 + threadIdx.x;
    if (idx >= NROWS * 10) return;
    int r = idx / 10;
    int pair = idx - r * 10;
    int j0 = 2 * pair;
    HP p0 = resolve_head(j0, Wp, bp, Wbu, bbu, W3, b3, W8, b8, Wa, ba, Wpp, bpp);
    HP p1 = resolve_head(j0 + 1, Wp, bp, Wbu, bbu, W3, b3, W8, b8, Wa, ba, Wpp, bpp);
    const ushort* hr = h1 + (size_t)r * 512;
    float s0 = 0.0f, s1 = 0.0f;
    for (int k = 0; k < 512; k += 8) {
        union { uint4 u4; ushort us[8]; } hu;
        hu.u4 = *(const uint4*)(hr + k);
#pragma unroll
        for (int u = 0; u < 8; u++) {
            float hv = fmaxf(bf16_to_f32(hu.us[u]), 0.0f);   // relu
            s0 += hv * p0.W[(k + u) * p0.nc + p0.lc];
            s1 += hv * p1.W[(k + u) * p1.nc + p1.lc];
        }
    }
    s0 += p0.bs[p0.lc];
    s1 += p1.bs[p1.lc];
    if (pair == 0) {   // ppi softmax over 2 logits
        float mx = fmaxf(s0, s1);
        float e0 = expf(s0 - mx), e1 = expf(s1 - mx);
        float inv = 1.0f / (e0 + e1);
        out[(size_t)r * 2]     = e0 * inv;
        out[(size_t)r * 2 + 1] = e1 * inv;
    } else {
        out[p0.off + (size_t)r * p0.nc + p0.lc] = s0;
        out[p1.off + (size_t)r * p1.nc + p1.lc] = s1;
    }
}

extern "C" void kernel_launch(void* const* d_in, const int* in_sizes, int n_in,
                              void* d_out, int out_size, void* d_ws, size_t ws_size,
                              hipStream_t stream) {
    const float* x    = (const float*)d_in[0];
    const int* xmask  = (const int*)d_in[1];
    const float* Wf0  = (const float*)d_in[3];
    const float* Uf0  = (const float*)d_in[4];
    const float* bf0  = (const float*)d_in[5];
    const float* Wb0  = (const float*)d_in[6];
    const float* Ub0  = (const float*)d_in[7];
    const float* bb0  = (const float*)d_in[8];
    const float* Wf1  = (const float*)d_in[9];
    const float* Uf1  = (const float*)d_in[10];
    const float* bf1  = (const float*)d_in[11];
    const float* Wb1  = (const float*)d_in[12];
    const float* Ub1  = (const float*)d_in[13];
    const float* bb1  = (const float*)d_in[14];
    const float* Wp   = (const float*)d_in[15]; const float* bp  = (const float*)d_in[16];
    const float* Wbu  = (const float*)d_in[17]; const float* bbu = (const float*)d_in[18];
    const float* W3   = (const float*)d_in[19]; const float* b3  = (const float*)d_in[20];
    const float* W8   = (const float*)d_in[21]; const float* b8  = (const float*)d_in[22];
    const float* Wa   = (const float*)d_in[23]; const float* ba  = (const float*)d_in[24];
    const float* Wpp  = (const float*)d_in[25]; const float* bpp = (const float*)d_in[26];
    float* out = (float*)d_out;

    char* ws = (char*)d_ws;
    size_t off = 0;
    auto take = [&](size_t bytes) -> void* {
        void* p = ws + off;
        off += (bytes + 255) & ~(size_t)255;
        return p;
    };
    int*    flags  = (int*)take(512 * 4);
    float*  hx     = (float*)take((size_t)64 * 2 * 256 * 4);
    float*  cstate = (float*)take((size_t)64 * 256 * 4);
    float*  h0F    = (float*)take((size_t)NROWS * 512 * 4);    // 134.2 MB, layer-0 h (f32)
    ushort* h1B    = (ushort*)take((size_t)NROWS * 512 * 2);   // 67.1 MB, layer-1 h (bf16)
    size_t fixed = off;

    // adaptive chunk: xW f32 chunk buffers cost S*262144 bytes (both dirs)
    int S = 8, lsS = 3;
    for (int cand = 11; cand >= 3; cand--) {
        if (fixed + (((size_t)1 << cand) * 262144) + 4096 <= ws_size) { S = 1 << cand; lsS = cand; break; }
    }
    float* xWcf = (float*)take((size_t)BATCH * S * NG * 4);
    float* xWcb = (float*)take((size_t)BATCH * S * NG * 4);
    int NC = T_SEQ / S;
    (void)in_sizes; (void)n_in; (void)out_size;

    init_flags_kernel<<<2, 256, 0, stream>>>(flags);

    dim3 ggrid(NG / 128, (BATCH * S) / 128);
    // layer 0: A = x (f32, K=64), writes h0F (f32)
    for (int c = 0; c < NC; c++) {
        int cb = c * S;
        gemm_split_kernel<<<ggrid, 256, 0, stream>>>(x, 64, Wf0, bf0, xWcf, cb, lsS, 0);
        gemm_split_kernel<<<ggrid, 256, 0, stream>>>(x, 64, Wb0, bb0, xWcb, cb, lsS, 1);
        lstm_kernel<<<256, 512, 0, stream>>>(Uf0, Ub0, xWcf, xWcb, xmask, h0F, nullptr,
                                             hx, cstate, flags, cb, S);
    }
    // layer 1: A = h0F (f32, K=512, read-only), writes h1B (bf16)
    for (int c = 0; c < NC; c++) {
        int cb = c * S;
        gemm_split_kernel<<<ggrid, 256, 0, stream>>>(h0F, 512, Wf1, bf1, xWcf, cb, lsS, 0);
        gemm_split_kernel<<<ggrid, 256, 0, stream>>>(h0F, 512, Wb1, bb1, xWcb, cb, lsS, 1);
        lstm_kernel<<<256, 512, 0, stream>>>(Uf1, Ub1, xWcf, xWcb, xmask, nullptr, h1B,
                                             hx, cstate, flags + 256, cb, S);
    }

    heads_kernel<<<(NROWS * 10 + 255) / 256, 256, 0, stream>>>(
        h1B, Wp, bp, Wbu, bbu, W3, b3, W8, b8, Wa, ba, Wpp, bpp, out);
}

// Round 8
// 36125.101 us; speedup vs baseline: 2.0170x; 1.3257x over previous
//
#include <hip/hip_runtime.h>
#include <stdint.h>

// BiRNN: 2-layer BiLSTM (U=256) + heads. B=32, T=2048, F=64.
// R8 (exchange latency): (1) chain = wg&63, w = wg>>6 so all 4 WGs of a chain
// land on the same XCD (blockIdx%8 round-robin) -> flag/h exchange stays in
// the shared per-XCD L2; (2) only lane 0 of each gather wave polls the flag
// (64x less atomic poll traffic); (3) flags padded to 128 B/chain (no false
// sharing). Protocol semantics identical to the passing R6/R7 kernels.

#define T_SEQ 2048
#define BATCH 32
#define NROWS 65536   // B*T
#define NG 1024       // 4*U
#define FLG_STRIDE 32 // ints per chain (128 B)

typedef __attribute__((ext_vector_type(8))) short short8;
typedef __attribute__((ext_vector_type(4))) float f32x4;
typedef __attribute__((ext_vector_type(2))) float f32x2;

__device__ __forceinline__ ushort f32_to_bf16(float f) {
    uint32_t u = __float_as_uint(f);
    u = u + 0x7FFFu + ((u >> 16) & 1u);   // RNE
    return (ushort)(u >> 16);
}
__device__ __forceinline__ float bf16_to_f32(ushort h) {
    return __uint_as_float(((uint32_t)h) << 16);
}
__device__ __forceinline__ uint64_t split_pack4(f32x4 v, uint64_t& lo64) {
    ushort h0 = f32_to_bf16(v[0]), h1 = f32_to_bf16(v[1]);
    ushort h2 = f32_to_bf16(v[2]), h3 = f32_to_bf16(v[3]);
    ushort l0 = f32_to_bf16(v[0] - bf16_to_f32(h0));
    ushort l1 = f32_to_bf16(v[1] - bf16_to_f32(h1));
    ushort l2 = f32_to_bf16(v[2] - bf16_to_f32(h2));
    ushort l3 = f32_to_bf16(v[3] - bf16_to_f32(h3));
    lo64 = (uint64_t)l0 | ((uint64_t)l1 << 16) | ((uint64_t)l2 << 32) | ((uint64_t)l3 << 48);
    return (uint64_t)h0 | ((uint64_t)h1 << 16) | ((uint64_t)h2 << 32) | ((uint64_t)h3 << 48);
}

__global__ void init_flags_kernel(int* __restrict__ flags, int n) {
    int i = blockIdx.x * 256 + threadIdx.x;
    if (i < n) flags[i] = 0;
}

// Chunked split-GEMM: Cc[b*S+loc][:] = A[row_g][:] @ Bw + bias (all f32 I/O).
__global__ __launch_bounds__(256) void gemm_split_kernel(
    const float* __restrict__ A, int K,
    const float* __restrict__ Bw, const float* __restrict__ bias,
    float* __restrict__ Cc, int cb, int lsS, int dir)
{
    __shared__ __align__(16) ushort Ash[128 * 36];
    __shared__ __align__(16) ushort Asl[128 * 36];
    __shared__ __align__(16) ushort Bsh[128 * 36];
    __shared__ __align__(16) ushort Bsl[128 * 36];
    const int Smask = (1 << lsS) - 1;
    int t = threadIdx.x;
    int n0 = blockIdx.x * 128;
    int m0 = blockIdx.y * 128;
    int lane = t & 63, wv = t >> 6;
    int wr = wv >> 1, wc = wv & 1;
    int fr = lane & 15, fq = lane >> 4;

    f32x4 acc[4][4];
#pragma unroll
    for (int i = 0; i < 4; i++)
#pragma unroll
        for (int j = 0; j < 4; j++) acc[i][j] = (f32x4)(0.0f);

    int arow = t >> 1, ahalf = t & 1;
    int bc = t & 127, bkh = t >> 7;

    int loc_all = m0 + arow;
    int b = loc_all >> lsS;
    int loc = loc_all & Smask;
    int row_g = b * T_SEQ + (dir ? (T_SEQ - 1 - cb - loc) : (cb + loc));

    for (int k0 = 0; k0 < K; k0 += 32) {
        {   // stage A tile 128x32: 16 f32 per thread, split to hi/lo
            const float* s = A + (size_t)row_g * K + k0 + ahalf * 16;
            uint64_t* dh = (uint64_t*)&Ash[arow * 36 + ahalf * 16];
            uint64_t* dl = (uint64_t*)&Asl[arow * 36 + ahalf * 16];
#pragma unroll
            for (int g = 0; g < 4; g++) {
                f32x4 v = ((const f32x4*)s)[g];
                uint64_t lo64;
                uint64_t hi64 = split_pack4(v, lo64);
                dh[g] = hi64; dl[g] = lo64;
            }
        }
        {   // stage B tile 32x128 transposed -> [c][k], split to hi/lo
            float bv[16];
#pragma unroll
            for (int i = 0; i < 16; i++)
                bv[i] = Bw[(size_t)(k0 + bkh * 16 + i) * NG + n0 + bc];
            uint64_t* dh = (uint64_t*)&Bsh[bc * 36 + bkh * 16];
            uint64_t* dl = (uint64_t*)&Bsl[bc * 36 + bkh * 16];
#pragma unroll
            for (int g = 0; g < 4; g++) {
                f32x4 v = { bv[4 * g], bv[4 * g + 1], bv[4 * g + 2], bv[4 * g + 3] };
                uint64_t lo64;
                uint64_t hi64 = split_pack4(v, lo64);
                dh[g] = hi64; dl[g] = lo64;
            }
        }
        __syncthreads();
        union FU { uint64_t u[2]; short8 v; };
        FU bh[4], bl[4];
#pragma unroll
        for (int n = 0; n < 4; n++) {
            int boff = (wc * 64 + n * 16 + fr) * 36 + fq * 8;
            bh[n].u[0] = ((const uint64_t*)&Bsh[boff])[0];
            bh[n].u[1] = ((const uint64_t*)&Bsh[boff])[1];
            bl[n].u[0] = ((const uint64_t*)&Bsl[boff])[0];
            bl[n].u[1] = ((const uint64_t*)&Bsl[boff])[1];
        }
#pragma unroll
        for (int m = 0; m < 4; m++) {
            int aoff = (wr * 64 + m * 16 + fr) * 36 + fq * 8;
            FU ah, al;
            ah.u[0] = ((const uint64_t*)&Ash[aoff])[0];
            ah.u[1] = ((const uint64_t*)&Ash[aoff])[1];
            al.u[0] = ((const uint64_t*)&Asl[aoff])[0];
            al.u[1] = ((const uint64_t*)&Asl[aoff])[1];
#pragma unroll
            for (int n = 0; n < 4; n++) {
                acc[m][n] = __builtin_amdgcn_mfma_f32_16x16x32_bf16(ah.v, bh[n].v, acc[m][n], 0, 0, 0);
                acc[m][n] = __builtin_amdgcn_mfma_f32_16x16x32_bf16(ah.v, bl[n].v, acc[m][n], 0, 0, 0);
                acc[m][n] = __builtin_amdgcn_mfma_f32_16x16x32_bf16(al.v, bh[n].v, acc[m][n], 0, 0, 0);
            }
        }
        __syncthreads();
    }
#pragma unroll
    for (int m = 0; m < 4; m++)
#pragma unroll
        for (int n = 0; n < 4; n++) {
            int gcol = n0 + wc * 64 + n * 16 + fr;
            float bvv = bias[gcol];
#pragma unroll
            for (int i = 0; i < 4; i++) {
                int crow = m0 + wr * 64 + m * 16 + fq * 4 + i;
                Cc[(size_t)crow * NG + gcol] = acc[m][n][i] + bvv;
            }
        }
}

// One chunk of S steps for 2 LSTMs (fwd+bwd). 256 WGs.
// chain = wg&63, w = wg>>6  => all 4 parts of a chain on one XCD (bid%8).
__global__ __launch_bounds__(512, 2) void lstm_kernel(
    const float* __restrict__ Uf, const float* __restrict__ Ub,
    const float* __restrict__ xWcf, const float* __restrict__ xWcb,  // [B][S][NG] f32
    const int* __restrict__ mask,
    float* __restrict__ houtF,             // [NROWS][512] f32, +dir*256 (or null)
    ushort* __restrict__ houtB,            // [NROWS][512] bf16, +dir*256 (or null)
    float* __restrict__ hx,                // [64][2][256] parity by global step
    float* __restrict__ cstate,            // [64][256]
    int* __restrict__ flags,               // [64][FLG_STRIDE], monotone global step
    int cb, int S)
{
    int wg = blockIdx.x;
    int chain = wg & 63;
    int w = wg >> 6;
    int dir = chain >> 5;
    int b = chain & 31;
    const float* U = dir ? Ub : Uf;
    const float* xWc = dir ? xWcb : xWcf;

    int t = threadIdx.x;
    __shared__ __align__(16) float hbuf[256];
    __shared__ __align__(16) float pbuf[4 * 256];

    int kchunk = t >> 7;
    int cg = t & 127;
    int q = cg >> 5;
    int jj0 = 2 * (cg & 31);
    int col0 = q * 256 + w * 64 + jj0;

    // U slice in registers: 64 k x 2 cols = 128 VGPRs
    f32x2 Ur[64];
    {
        const float* Up = U + (size_t)(kchunk * 64) * NG + col0;
#pragma unroll
        for (int i = 0; i < 64; i++) Ur[i] = *(const f32x2*)(Up + (size_t)i * NG);
    }
    float* hxc = hx + chain * 512;
    int* flg = flags + chain * FLG_STRIDE;
    int j = t & 63;
    int gj = w * 64 + j;
    if (t < 256) hbuf[t] = (cb == 0) ? 0.0f : hxc[((cb - 1) & 1) * 256 + t];
    float creg = 0.0f, hreg = 0.0f;
    if (t < 64 && cb != 0) {
        creg = cstate[chain * 256 + gj];
        hreg = hxc[((cb - 1) & 1) * 256 + gj];
    }
    int owner = t >> 6;
    __syncthreads();

    for (int nl = 0; nl < S; nl++) {
        int n = cb + nl;
        int tp = dir ? (T_SEQ - 1 - n) : n;
        size_t row_g = (size_t)b * T_SEQ + tp;
        // cell threads issue their 4 xW loads + mask early (hidden under spin)
        float xw0 = 0.f, xw1 = 0.f, xw2 = 0.f, xw3 = 0.f;
        int mval = 0;
        if (t < 64) {
            const float* xr = xWc + ((size_t)b * S + nl) * NG;
            xw0 = xr[gj];
            xw1 = xr[256 + gj];
            xw2 = xr[512 + gj];
            xw3 = xr[768 + gj];
            mval = mask[row_g];
        }
        // gather foreign h slices: lane 0 of each gather wave polls (relaxed),
        // one acquire confirm; whole wave then loads hx (atomic relaxed -> L2).
        if (n > 0 && t < 256 && owner != w) {
            if (j == 0) {
                while (__hip_atomic_load(&flg[owner], __ATOMIC_RELAXED, __HIP_MEMORY_SCOPE_AGENT) < n)
                    __builtin_amdgcn_s_sleep(1);
                (void)__hip_atomic_load(&flg[owner], __ATOMIC_ACQUIRE, __HIP_MEMORY_SCOPE_AGENT);
            }
            hbuf[t] = __hip_atomic_load(&hxc[((n - 1) & 1) * 256 + t], __ATOMIC_RELAXED, __HIP_MEMORY_SCOPE_AGENT);
        }
        __syncthreads();   // (C)
        // partial dot: 2 cols x 64 k, exact f32 FMA, U in registers
        float a0 = 0.0f, a1 = 0.0f;
        {
            const float* hb = &hbuf[kchunk * 64];
#pragma unroll
            for (int i = 0; i < 16; i++) {
                f32x4 h4 = *(const f32x4*)(hb + 4 * i);
#pragma unroll
                for (int j2 = 0; j2 < 4; j2++) {
                    a0 += h4[j2] * Ur[4 * i + j2][0];
                    a1 += h4[j2] * Ur[4 * i + j2][1];
                }
            }
        }
        {
            f32x2 pv = {a0, a1};
            *(f32x2*)&pbuf[kchunk * 256 + 2 * cg] = pv;
        }
        __syncthreads();   // (E)
        if (t < 64) {
            float zi = xw0 + pbuf[j]       + pbuf[256 + j]       + pbuf[512 + j]       + pbuf[768 + j];
            float zf = xw1 + pbuf[64 + j]  + pbuf[256 + 64 + j]  + pbuf[512 + 64 + j]  + pbuf[768 + 64 + j];
            float zg = xw2 + pbuf[128 + j] + pbuf[256 + 128 + j] + pbuf[512 + 128 + j] + pbuf[768 + 128 + j];
            float zo = xw3 + pbuf[192 + j] + pbuf[256 + 192 + j] + pbuf[512 + 192 + j] + pbuf[768 + 192 + j];
            float ig = 1.0f / (1.0f + expf(-zi));
            float fg = 1.0f / (1.0f + expf(-zf));
            float gg = tanhf(zg);
            float og = 1.0f / (1.0f + expf(-zo));
            float cn = fg * creg + ig * gg;
            float hn = og * tanhf(cn);
            if (mval == 1) { hn = hreg; cn = creg; }   // x_mask==1 -> hold
            creg = cn; hreg = hn;
            hbuf[gj] = hn;
            size_t oidx = row_g * 512 + dir * 256 + gj;
            if (houtF) houtF[oidx] = hn;
            else       houtB[oidx] = f32_to_bf16(hn);
            __hip_atomic_store(&hxc[(n & 1) * 256 + gj], hn, __ATOMIC_RELAXED, __HIP_MEMORY_SCOPE_AGENT);
            if (t == 0)
                __hip_atomic_store(&flg[w], n + 1, __ATOMIC_RELEASE, __HIP_MEMORY_SCOPE_AGENT);
        }
    }
    if (t < 64) cstate[chain * 256 + gj] = creg;
}

struct HP { const float* W; const float* bs; int nc; int lc; size_t off; };
__device__ __forceinline__ HP resolve_head(int j,
    const float* Wp, const float* bp, const float* Wbu, const float* bbu,
    const float* W3, const float* b3, const float* W8, const float* b8,
    const float* Wa, const float* ba, const float* Wpp, const float* bpp)
{
    HP h;
    if (j < 2)       { h.W = Wp;  h.bs = bp;  h.nc = 2; h.lc = j;      h.off = 0; }
    else if (j < 4)  { h.W = Wbu; h.bs = bbu; h.nc = 2; h.lc = j - 2;  h.off = (size_t)NROWS * 2; }
    else if (j < 7)  { h.W = W3;  h.bs = b3;  h.nc = 3; h.lc = j - 4;  h.off = (size_t)NROWS * 4; }
    else if (j < 15) { h.W = W8;  h.bs = b8;  h.nc = 8; h.lc = j - 7;  h.off = (size_t)NROWS * 7; }
    else if (j < 16) { h.W = Wa;  h.bs = ba;  h.nc = 1; h.lc = 0;      h.off = (size_t)NROWS * 15; }
    else             { h.W = Wpp; h.bs = bpp; h.nc = 4; h.lc = j - 16; h.off = (size_t)NROWS * 16; }
    return h;
}

__global__ __launch_bounds__(256) void heads_kernel(
    const ushort* __restrict__ h1,   // [NROWS][512] bf16
    const float* __restrict__ Wp, const float* __restrict__ bp,
    const float* __restrict__ Wbu, const float* __restrict__ bbu,
    const float* __restrict__ W3, const float* __restrict__ b3,
    const float* __restrict__ W8, const float* __restrict__ b8,
    const float* __restrict__ Wa, const float* __restrict__ ba,
    const float* __restrict__ Wpp, const float* __restrict__ bpp,
    float* __restrict__ out)
{
    int idx = blockIdx.x * 256 + threadIdx.x;
    if (idx >= NROWS * 10) return;
    int r = idx / 10;
    int pair = idx - r * 10;
    int j0 = 2 * pair;
    HP p0 = resolve_head(j0, Wp, bp, Wbu, bbu, W3, b3, W8, b8, Wa, ba, Wpp, bpp);
    HP p1 = resolve_head(j0 + 1, Wp, bp, Wbu, bbu, W3, b3, W8, b8, Wa, ba, Wpp, bpp);
    const ushort* hr = h1 + (size_t)r * 512;
    float s0 = 0.0f, s1 = 0.0f;
    for (int k = 0; k < 512; k += 8) {
        union { uint4 u4; ushort us[8]; } hu;
        hu.u4 = *(const uint4*)(hr + k);
#pragma unroll
        for (int u = 0; u < 8; u++) {
            float hv = fmaxf(bf16_to_f32(hu.us[u]), 0.0f);   // relu
            s0 += hv * p0.W[(k + u) * p0.nc + p0.lc];
            s1 += hv * p1.W[(k + u) * p1.nc + p1.lc];
        }
    }
    s0 += p0.bs[p0.lc];
    s1 += p1.bs[p1.lc];
    if (pair == 0) {   // ppi softmax over 2 logits
        float mx = fmaxf(s0, s1);
        float e0 = expf(s0 - mx), e1 = expf(s1 - mx);
        float inv = 1.0f / (e0 + e1);
        out[(size_t)r * 2]     = e0 * inv;
        out[(size_t)r * 2 + 1] = e1 * inv;
    } else {
        out[p0.off + (size_t)r * p0.nc + p0.lc] = s0;
        out[p1.off + (size_t)r * p1.nc + p1.lc] = s1;
    }
}

extern "C" void kernel_launch(void* const* d_in, const int* in_sizes, int n_in,
                              void* d_out, int out_size, void* d_ws, size_t ws_size,
                              hipStream_t stream) {
    const float* x    = (const float*)d_in[0];
    const int* xmask  = (const int*)d_in[1];
    const float* Wf0  = (const float*)d_in[3];
    const float* Uf0  = (const float*)d_in[4];
    const float* bf0  = (const float*)d_in[5];
    const float* Wb0  = (const float*)d_in[6];
    const float* Ub0  = (const float*)d_in[7];
    const float* bb0  = (const float*)d_in[8];
    const float* Wf1  = (const float*)d_in[9];
    const float* Uf1  = (const float*)d_in[10];
    const float* bf1  = (const float*)d_in[11];
    const float* Wb1  = (const float*)d_in[12];
    const float* Ub1  = (const float*)d_in[13];
    const float* bb1  = (const float*)d_in[14];
    const float* Wp   = (const float*)d_in[15]; const float* bp  = (const float*)d_in[16];
    const float* Wbu  = (const float*)d_in[17]; const float* bbu = (const float*)d_in[18];
    const float* W3   = (const float*)d_in[19]; const float* b3  = (const float*)d_in[20];
    const float* W8   = (const float*)d_in[21]; const float* b8  = (const float*)d_in[22];
    const float* Wa   = (const float*)d_in[23]; const float* ba  = (const float*)d_in[24];
    const float* Wpp  = (const float*)d_in[25]; const float* bpp = (const float*)d_in[26];
    float* out = (float*)d_out;

    char* ws = (char*)d_ws;
    size_t off = 0;
    auto take = [&](size_t bytes) -> void* {
        void* p = ws + off;
        off += (bytes + 255) & ~(size_t)255;
        return p;
    };
    int*    flags  = (int*)take((size_t)2 * 64 * FLG_STRIDE * 4);   // layer0 + layer1
    float*  hx     = (float*)take((size_t)64 * 2 * 256 * 4);
    float*  cstate = (float*)take((size_t)64 * 256 * 4);
    float*  h0F    = (float*)take((size_t)NROWS * 512 * 4);    // 134.2 MB (f32)
    ushort* h1B    = (ushort*)take((size_t)NROWS * 512 * 2);   // 67.1 MB (bf16)
    size_t fixed = off;

    // adaptive chunk: xW f32 chunk buffers cost S*262144 bytes (both dirs)
    int S = 8, lsS = 3;
    for (int cand = 11; cand >= 3; cand--) {
        if (fixed + (((size_t)1 << cand) * 262144) + 4096 <= ws_size) { S = 1 << cand; lsS = cand; break; }
    }
    float* xWcf = (float*)take((size_t)BATCH * S * NG * 4);
    float* xWcb = (float*)take((size_t)BATCH * S * NG * 4);
    int NC = T_SEQ / S;
    (void)in_sizes; (void)n_in; (void)out_size;

    init_flags_kernel<<<(2 * 64 * FLG_STRIDE + 255) / 256, 256, 0, stream>>>(flags, 2 * 64 * FLG_STRIDE);

    dim3 ggrid(NG / 128, (BATCH * S) / 128);
    // layer 0: A = x (f32, K=64), writes h0F (f32)
    for (int c = 0; c < NC; c++) {
        int cb = c * S;
        gemm_split_kernel<<<ggrid, 256, 0, stream>>>(x, 64, Wf0, bf0, xWcf, cb, lsS, 0);
        gemm_split_kernel<<<ggrid, 256, 0, stream>>>(x, 64, Wb0, bb0, xWcb, cb, lsS, 1);
        lstm_kernel<<<256, 512, 0, stream>>>(Uf0, Ub0, xWcf, xWcb, xmask, h0F, nullptr,
                                             hx, cstate, flags, cb, S);
    }
    // layer 1: A = h0F (f32, K=512, read-only), writes h1B (bf16)
    for (int c = 0; c < NC; c++) {
        int cb = c * S;
        gemm_split_kernel<<<ggrid, 256, 0, stream>>>(h0F, 512, Wf1, bf1, xWcf, cb, lsS, 0);
        gemm_split_kernel<<<ggrid, 256, 0, stream>>>(h0F, 512, Wb1, bb1, xWcb, cb, lsS, 1);
        lstm_kernel<<<256, 512, 0, stream>>>(Uf1, Ub1, xWcf, xWcb, xmask, nullptr, h1B,
                                             hx, cstate, flags + 64 * FLG_STRIDE, cb, S);
    }

    heads_kernel<<<(NROWS * 10 + 255) / 256, 256, 0, stream>>>(
        h1B, Wp, bp, Wbu, bbu, W3, b3, W8, b8, Wa, ba, Wpp, bpp, out);
}

// Round 9
// 20530.775 us; speedup vs baseline: 3.5491x; 1.7596x over previous
//
#include <hip/hip_runtime.h>
#include <stdint.h>

// BiRNN: 2-layer BiLSTM (U=256) + heads. B=32, T=2048, F=64.
// R9: mask-aware exchange — x_mask==1 (~50% of steps) holds h,c, so those
// steps skip the entire inter-WG exchange (no xW read, no dot, no hx store,
// no flag bump, no poll). Protocol re-indexed by publish count kc:
//   flag[w] = #publishes by WG w; publish j stored at hx parity (j-1)&1;
//   active step: gather peers' publish kc (poll flg>=kc), compute, publish
//   kc+1 at parity kc&1. Same overwrite-safety induction as R6-R8 (passing).
// Also: per-chunk mask preloaded into LDS (off the serial path).

#define T_SEQ 2048
#define BATCH 32
#define NROWS 65536   // B*T
#define NG 1024       // 4*U
#define FLG_STRIDE 32 // ints per chain (128 B)

typedef __attribute__((ext_vector_type(8))) short short8;
typedef __attribute__((ext_vector_type(4))) float f32x4;
typedef __attribute__((ext_vector_type(2))) float f32x2;

__device__ __forceinline__ ushort f32_to_bf16(float f) {
    uint32_t u = __float_as_uint(f);
    u = u + 0x7FFFu + ((u >> 16) & 1u);   // RNE
    return (ushort)(u >> 16);
}
__device__ __forceinline__ float bf16_to_f32(ushort h) {
    return __uint_as_float(((uint32_t)h) << 16);
}
__device__ __forceinline__ uint64_t split_pack4(f32x4 v, uint64_t& lo64) {
    ushort h0 = f32_to_bf16(v[0]), h1 = f32_to_bf16(v[1]);
    ushort h2 = f32_to_bf16(v[2]), h3 = f32_to_bf16(v[3]);
    ushort l0 = f32_to_bf16(v[0] - bf16_to_f32(h0));
    ushort l1 = f32_to_bf16(v[1] - bf16_to_f32(h1));
    ushort l2 = f32_to_bf16(v[2] - bf16_to_f32(h2));
    ushort l3 = f32_to_bf16(v[3] - bf16_to_f32(h3));
    lo64 = (uint64_t)l0 | ((uint64_t)l1 << 16) | ((uint64_t)l2 << 32) | ((uint64_t)l3 << 48);
    return (uint64_t)h0 | ((uint64_t)h1 << 16) | ((uint64_t)h2 << 32) | ((uint64_t)h3 << 48);
}

__global__ void init_flags_kernel(int* __restrict__ flags, int n) {
    int i = blockIdx.x * 256 + threadIdx.x;
    if (i < n) flags[i] = 0;
}

// Chunked split-GEMM: Cc[b*S+loc][:] = A[row_g][:] @ Bw + bias (all f32 I/O).
__global__ __launch_bounds__(256) void gemm_split_kernel(
    const float* __restrict__ A, int K,
    const float* __restrict__ Bw, const float* __restrict__ bias,
    float* __restrict__ Cc, int cb, int lsS, int dir)
{
    __shared__ __align__(16) ushort Ash[128 * 36];
    __shared__ __align__(16) ushort Asl[128 * 36];
    __shared__ __align__(16) ushort Bsh[128 * 36];
    __shared__ __align__(16) ushort Bsl[128 * 36];
    const int Smask = (1 << lsS) - 1;
    int t = threadIdx.x;
    int n0 = blockIdx.x * 128;
    int m0 = blockIdx.y * 128;
    int lane = t & 63, wv = t >> 6;
    int wr = wv >> 1, wc = wv & 1;
    int fr = lane & 15, fq = lane >> 4;

    f32x4 acc[4][4];
#pragma unroll
    for (int i = 0; i < 4; i++)
#pragma unroll
        for (int j = 0; j < 4; j++) acc[i][j] = (f32x4)(0.0f);

    int arow = t >> 1, ahalf = t & 1;
    int bc = t & 127, bkh = t >> 7;

    int loc_all = m0 + arow;
    int b = loc_all >> lsS;
    int loc = loc_all & Smask;
    int row_g = b * T_SEQ + (dir ? (T_SEQ - 1 - cb - loc) : (cb + loc));

    for (int k0 = 0; k0 < K; k0 += 32) {
        {   // stage A tile 128x32: 16 f32 per thread, split to hi/lo
            const float* s = A + (size_t)row_g * K + k0 + ahalf * 16;
            uint64_t* dh = (uint64_t*)&Ash[arow * 36 + ahalf * 16];
            uint64_t* dl = (uint64_t*)&Asl[arow * 36 + ahalf * 16];
#pragma unroll
            for (int g = 0; g < 4; g++) {
                f32x4 v = ((const f32x4*)s)[g];
                uint64_t lo64;
                uint64_t hi64 = split_pack4(v, lo64);
                dh[g] = hi64; dl[g] = lo64;
            }
        }
        {   // stage B tile 32x128 transposed -> [c][k], split to hi/lo
            float bv[16];
#pragma unroll
            for (int i = 0; i < 16; i++)
                bv[i] = Bw[(size_t)(k0 + bkh * 16 + i) * NG + n0 + bc];
            uint64_t* dh = (uint64_t*)&Bsh[bc * 36 + bkh * 16];
            uint64_t* dl = (uint64_t*)&Bsl[bc * 36 + bkh * 16];
#pragma unroll
            for (int g = 0; g < 4; g++) {
                f32x4 v = { bv[4 * g], bv[4 * g + 1], bv[4 * g + 2], bv[4 * g + 3] };
                uint64_t lo64;
                uint64_t hi64 = split_pack4(v, lo64);
                dh[g] = hi64; dl[g] = lo64;
            }
        }
        __syncthreads();
        union FU { uint64_t u[2]; short8 v; };
        FU bh[4], bl[4];
#pragma unroll
        for (int n = 0; n < 4; n++) {
            int boff = (wc * 64 + n * 16 + fr) * 36 + fq * 8;
            bh[n].u[0] = ((const uint64_t*)&Bsh[boff])[0];
            bh[n].u[1] = ((const uint64_t*)&Bsh[boff])[1];
            bl[n].u[0] = ((const uint64_t*)&Bsl[boff])[0];
            bl[n].u[1] = ((const uint64_t*)&Bsl[boff])[1];
        }
#pragma unroll
        for (int m = 0; m < 4; m++) {
            int aoff = (wr * 64 + m * 16 + fr) * 36 + fq * 8;
            FU ah, al;
            ah.u[0] = ((const uint64_t*)&Ash[aoff])[0];
            ah.u[1] = ((const uint64_t*)&Ash[aoff])[1];
            al.u[0] = ((const uint64_t*)&Asl[aoff])[0];
            al.u[1] = ((const uint64_t*)&Asl[aoff])[1];
#pragma unroll
            for (int n = 0; n < 4; n++) {
                acc[m][n] = __builtin_amdgcn_mfma_f32_16x16x32_bf16(ah.v, bh[n].v, acc[m][n], 0, 0, 0);
                acc[m][n] = __builtin_amdgcn_mfma_f32_16x16x32_bf16(ah.v, bl[n].v, acc[m][n], 0, 0, 0);
                acc[m][n] = __builtin_amdgcn_mfma_f32_16x16x32_bf16(al.v, bh[n].v, acc[m][n], 0, 0, 0);
            }
        }
        __syncthreads();
    }
#pragma unroll
    for (int m = 0; m < 4; m++)
#pragma unroll
        for (int n = 0; n < 4; n++) {
            int gcol = n0 + wc * 64 + n * 16 + fr;
            float bvv = bias[gcol];
#pragma unroll
            for (int i = 0; i < 4; i++) {
                int crow = m0 + wr * 64 + m * 16 + fq * 4 + i;
                Cc[(size_t)crow * NG + gcol] = acc[m][n][i] + bvv;
            }
        }
}

// One chunk of S steps for 2 LSTMs (fwd+bwd). 256 WGs.
// chain = wg&63, w = wg>>6 (chain's 4 WGs co-located per blockIdx%8 XCD rr).
__global__ __launch_bounds__(512, 2) void lstm_kernel(
    const float* __restrict__ Uf, const float* __restrict__ Ub,
    const float* __restrict__ xWcf, const float* __restrict__ xWcb,  // [B][S][NG] f32
    const int* __restrict__ mask,
    float* __restrict__ houtF,             // [NROWS][512] f32, +dir*256 (or null)
    ushort* __restrict__ houtB,            // [NROWS][512] bf16, +dir*256 (or null)
    float* __restrict__ hx,                // [64][2][256]: publish j at parity (j-1)&1
    float* __restrict__ cstate,            // [64][256]
    int* __restrict__ flags,               // [64][FLG_STRIDE]: publish count
    int cb, int S)
{
    int wg = blockIdx.x;
    int chain = wg & 63;
    int w = wg >> 6;
    int dir = chain >> 5;
    int b = chain & 31;
    const float* U = dir ? Ub : Uf;
    const float* xWc = dir ? xWcb : xWcf;

    int t = threadIdx.x;
    __shared__ __align__(16) float hbuf[256];
    __shared__ __align__(16) float pbuf[4 * 256];
    __shared__ int mbuf[2048];

    int kchunk = t >> 7;
    int cg = t & 127;
    int q = cg >> 5;
    int jj0 = 2 * (cg & 31);
    int col0 = q * 256 + w * 64 + jj0;

    // U slice in registers: 64 k x 2 cols = 128 VGPRs
    f32x2 Ur[64];
    {
        const float* Up = U + (size_t)(kchunk * 64) * NG + col0;
#pragma unroll
        for (int i = 0; i < 64; i++) Ur[i] = *(const f32x2*)(Up + (size_t)i * NG);
    }
    float* hxc = hx + chain * 512;
    int* flg = flags + chain * FLG_STRIDE;
    int j = t & 63;
    int gj = w * 64 + j;
    int owner = t >> 6;

    // preload this chunk's mask into LDS
    for (int nl = t; nl < S; nl += 512) {
        int tp = dir ? (T_SEQ - 1 - (cb + nl)) : (cb + nl);
        mbuf[nl] = mask[b * T_SEQ + tp];
    }
    // publish count (all flags equal at kernel boundary)
    int kc = __hip_atomic_load(&flg[w], __ATOMIC_RELAXED, __HIP_MEMORY_SCOPE_AGENT);
    // restore hbuf = publish kc (complete at kernel boundary), zeros if none
    if (t < 256)
        hbuf[t] = (kc > 0)
            ? __hip_atomic_load(&hxc[((kc - 1) & 1) * 256 + t], __ATOMIC_RELAXED, __HIP_MEMORY_SCOPE_AGENT)
            : 0.0f;
    float creg = 0.0f, hreg = 0.0f;
    if (t < 64) {
        if (cb != 0) creg = cstate[chain * 256 + gj];
        if (kc > 0)
            hreg = __hip_atomic_load(&hxc[((kc - 1) & 1) * 256 + gj], __ATOMIC_RELAXED, __HIP_MEMORY_SCOPE_AGENT);
    }
    __syncthreads();

    for (int nl = 0; nl < S; nl++) {
        int tp = dir ? (T_SEQ - 1 - (cb + nl)) : (cb + nl);
        size_t row_g = (size_t)b * T_SEQ + tp;
        int mval = mbuf[nl];                 // uniform across WG (and chain)
        if (mval == 1) {
            // hold step: h,c unchanged; just emit output. No exchange at all.
            if (t < 64) {
                size_t oidx = row_g * 512 + dir * 256 + gj;
                if (houtF) houtF[oidx] = hreg;
                else       houtB[oidx] = f32_to_bf16(hreg);
            }
            continue;
        }
        // ---- active step ----
        float xw0 = 0.f, xw1 = 0.f, xw2 = 0.f, xw3 = 0.f;
        if (t < 64) {
            const float* xr = xWc + ((size_t)b * S + nl) * NG;
            xw0 = xr[gj];
            xw1 = xr[256 + gj];
            xw2 = xr[512 + gj];
            xw3 = xr[768 + gj];
        }
        // gather peers' publish kc (h state entering this step)
        if (kc > 0 && t < 256 && owner != w) {
            if (j == 0) {
                while (__hip_atomic_load(&flg[owner], __ATOMIC_RELAXED, __HIP_MEMORY_SCOPE_AGENT) < kc)
                    __builtin_amdgcn_s_sleep(1);
                (void)__hip_atomic_load(&flg[owner], __ATOMIC_ACQUIRE, __HIP_MEMORY_SCOPE_AGENT);
            }
            hbuf[t] = __hip_atomic_load(&hxc[((kc - 1) & 1) * 256 + t], __ATOMIC_RELAXED, __HIP_MEMORY_SCOPE_AGENT);
        }
        __syncthreads();   // (C)
        // partial dot: 2 cols x 64 k, exact f32 FMA, U in registers
        float a0 = 0.0f, a1 = 0.0f;
        {
            const float* hb = &hbuf[kchunk * 64];
#pragma unroll
            for (int i = 0; i < 16; i++) {
                f32x4 h4 = *(const f32x4*)(hb + 4 * i);
#pragma unroll
                for (int j2 = 0; j2 < 4; j2++) {
                    a0 += h4[j2] * Ur[4 * i + j2][0];
                    a1 += h4[j2] * Ur[4 * i + j2][1];
                }
            }
        }
        {
            f32x2 pv = {a0, a1};
            *(f32x2*)&pbuf[kchunk * 256 + 2 * cg] = pv;
        }
        __syncthreads();   // (E)
        if (t < 64) {
            float zi = xw0 + pbuf[j]       + pbuf[256 + j]       + pbuf[512 + j]       + pbuf[768 + j];
            float zf = xw1 + pbuf[64 + j]  + pbuf[256 + 64 + j]  + pbuf[512 + 64 + j]  + pbuf[768 + 64 + j];
            float zg = xw2 + pbuf[128 + j] + pbuf[256 + 128 + j] + pbuf[512 + 128 + j] + pbuf[768 + 128 + j];
            float zo = xw3 + pbuf[192 + j] + pbuf[256 + 192 + j] + pbuf[512 + 192 + j] + pbuf[768 + 192 + j];
            float ig = 1.0f / (1.0f + expf(-zi));
            float fg = 1.0f / (1.0f + expf(-zf));
            float gg = tanhf(zg);
            float og = 1.0f / (1.0f + expf(-zo));
            float cn = fg * creg + ig * gg;
            float hn = og * tanhf(cn);
            creg = cn; hreg = hn;
            hbuf[gj] = hn;
            size_t oidx = row_g * 512 + dir * 256 + gj;
            if (houtF) houtF[oidx] = hn;
            else       houtB[oidx] = f32_to_bf16(hn);
            // publish kc+1 at parity kc&1
            __hip_atomic_store(&hxc[(kc & 1) * 256 + gj], hn, __ATOMIC_RELAXED, __HIP_MEMORY_SCOPE_AGENT);
            if (t == 0)
                __hip_atomic_store(&flg[w], kc + 1, __ATOMIC_RELEASE, __HIP_MEMORY_SCOPE_AGENT);
        }
        kc++;   // uniform across WG
    }
    if (t < 64) cstate[chain * 256 + gj] = creg;
}

struct HP { const float* W; const float* bs; int nc; int lc; size_t off; };
__device__ __forceinline__ HP resolve_head(int j,
    const float* Wp, const float* bp, const float* Wbu, const float* bbu,
    const float* W3, const float* b3, const float* W8, const float* b8,
    const float* Wa, const float* ba, const float* Wpp, const float* bpp)
{
    HP h;
    if (j < 2)       { h.W = Wp;  h.bs = bp;  h.nc = 2; h.lc = j;      h.off = 0; }
    else if (j < 4)  { h.W = Wbu; h.bs = bbu; h.nc = 2; h.lc = j - 2;  h.off = (size_t)NROWS * 2; }
    else if (j < 7)  { h.W = W3;  h.bs = b3;  h.nc = 3; h.lc = j - 4;  h.off = (size_t)NROWS * 4; }
    else if (j < 15) { h.W = W8;  h.bs = b8;  h.nc = 8; h.lc = j - 7;  h.off = (size_t)NROWS * 7; }
    else if (j < 16) { h.W = Wa;  h.bs = ba;  h.nc = 1; h.lc = 0;      h.off = (size_t)NROWS * 15; }
    else             { h.W = Wpp; h.bs = bpp; h.nc = 4; h.lc = j - 16; h.off = (size_t)NROWS * 16; }
    return h;
}

__global__ __launch_bounds__(256) void heads_kernel(
    const ushort* __restrict__ h1,   // [NROWS][512] bf16
    const float* __restrict__ Wp, const float* __restrict__ bp,
    const float* __restrict__ Wbu, const float* __restrict__ bbu,
    const float* __restrict__ W3, const float* __restrict__ b3,
    const float* __restrict__ W8, const float* __restrict__ b8,
    const float* __restrict__ Wa, const float* __restrict__ ba,
    const float* __restrict__ Wpp, const float* __restrict__ bpp,
    float* __restrict__ out)
{
    int idx = blockIdx.x * 256 + threadIdx.x;
    if (idx >= NROWS * 10) return;
    int r = idx / 10;
    int pair = idx - r * 10;
    int j0 = 2 * pair;
    HP p0 = resolve_head(j0, Wp, bp, Wbu, bbu, W3, b3, W8, b8, Wa, ba, Wpp, bpp);
    HP p1 = resolve_head(j0 + 1, Wp, bp, Wbu, bbu, W3, b3, W8, b8, Wa, ba, Wpp, bpp);
    const ushort* hr = h1 + (size_t)r * 512;
    float s0 = 0.0f, s1 = 0.0f;
    for (int k = 0; k < 512; k += 8) {
        union { uint4 u4; ushort us[8]; } hu;
        hu.u4 = *(const uint4*)(hr + k);
#pragma unroll
        for (int u = 0; u < 8; u++) {
            float hv = fmaxf(bf16_to_f32(hu.us[u]), 0.0f);   // relu
            s0 += hv * p0.W[(k + u) * p0.nc + p0.lc];
            s1 += hv * p1.W[(k + u) * p1.nc + p1.lc];
        }
    }
    s0 += p0.bs[p0.lc];
    s1 += p1.bs[p1.lc];
    if (pair == 0) {   // ppi softmax over 2 logits
        float mx = fmaxf(s0, s1);
        float e0 = expf(s0 - mx), e1 = expf(s1 - mx);
        float inv = 1.0f / (e0 + e1);
        out[(size_t)r * 2]     = e0 * inv;
        out[(size_t)r * 2 + 1] = e1 * inv;
    } else {
        out[p0.off + (size_t)r * p0.nc + p0.lc] = s0;
        out[p1.off + (size_t)r * p1.nc + p1.lc] = s1;
    }
}

extern "C" void kernel_launch(void* const* d_in, const int* in_sizes, int n_in,
                              void* d_out, int out_size, void* d_ws, size_t ws_size,
                              hipStream_t stream) {
    const float* x    = (const float*)d_in[0];
    const int* xmask  = (const int*)d_in[1];
    const float* Wf0  = (const float*)d_in[3];
    const float* Uf0  = (const float*)d_in[4];
    const float* bf0  = (const float*)d_in[5];
    const float* Wb0  = (const float*)d_in[6];
    const float* Ub0  = (const float*)d_in[7];
    const float* bb0  = (const float*)d_in[8];
    const float* Wf1  = (const float*)d_in[9];
    const float* Uf1  = (const float*)d_in[10];
    const float* bf1  = (const float*)d_in[11];
    const float* Wb1  = (const float*)d_in[12];
    const float* Ub1  = (const float*)d_in[13];
    const float* bb1  = (const float*)d_in[14];
    const float* Wp   = (const float*)d_in[15]; const float* bp  = (const float*)d_in[16];
    const float* Wbu  = (const float*)d_in[17]; const float* bbu = (const float*)d_in[18];
    const float* W3   = (const float*)d_in[19]; const float* b3  = (const float*)d_in[20];
    const float* W8   = (const float*)d_in[21]; const float* b8  = (const float*)d_in[22];
    const float* Wa   = (const float*)d_in[23]; const float* ba  = (const float*)d_in[24];
    const float* Wpp  = (const float*)d_in[25]; const float* bpp = (const float*)d_in[26];
    float* out = (float*)d_out;

    char* ws = (char*)d_ws;
    size_t off = 0;
    auto take = [&](size_t bytes) -> void* {
        void* p = ws + off;
        off += (bytes + 255) & ~(size_t)255;
        return p;
    };
    int*    flags  = (int*)take((size_t)2 * 64 * FLG_STRIDE * 4);   // layer0 + layer1
    float*  hx     = (float*)take((size_t)64 * 2 * 256 * 4);
    float*  cstate = (float*)take((size_t)64 * 256 * 4);
    float*  h0F    = (float*)take((size_t)NROWS * 512 * 4);    // 134.2 MB (f32)
    ushort* h1B    = (ushort*)take((size_t)NROWS * 512 * 2);   // 67.1 MB (bf16)
    size_t fixed = off;

    // adaptive chunk: xW f32 chunk buffers cost S*262144 bytes (both dirs)
    int S = 8, lsS = 3;
    for (int cand = 11; cand >= 3; cand--) {
        if (fixed + (((size_t)1 << cand) * 262144) + 4096 <= ws_size) { S = 1 << cand; lsS = cand; break; }
    }
    float* xWcf = (float*)take((size_t)BATCH * S * NG * 4);
    float* xWcb = (float*)take((size_t)BATCH * S * NG * 4);
    int NC = T_SEQ / S;
    (void)in_sizes; (void)n_in; (void)out_size;

    init_flags_kernel<<<(2 * 64 * FLG_STRIDE + 255) / 256, 256, 0, stream>>>(flags, 2 * 64 * FLG_STRIDE);

    dim3 ggrid(NG / 128, (BATCH * S) / 128);
    // layer 0: A = x (f32, K=64), writes h0F (f32)
    for (int c = 0; c < NC; c++) {
        int cb = c * S;
        gemm_split_kernel<<<ggrid, 256, 0, stream>>>(x, 64, Wf0, bf0, xWcf, cb, lsS, 0);
        gemm_split_kernel<<<ggrid, 256, 0, stream>>>(x, 64, Wb0, bb0, xWcb, cb, lsS, 1);
        lstm_kernel<<<256, 512, 0, stream>>>(Uf0, Ub0, xWcf, xWcb, xmask, h0F, nullptr,
                                             hx, cstate, flags, cb, S);
    }
    // layer 1: A = h0F (f32, K=512, read-only), writes h1B (bf16)
    for (int c = 0; c < NC; c++) {
        int cb = c * S;
        gemm_split_kernel<<<ggrid, 256, 0, stream>>>(h0F, 512, Wf1, bf1, xWcf, cb, lsS, 0);
        gemm_split_kernel<<<ggrid, 256, 0, stream>>>(h0F, 512, Wb1, bb1, xWcb, cb, lsS, 1);
        lstm_kernel<<<256, 512, 0, stream>>>(Uf1, Ub1, xWcf, xWcb, xmask, nullptr, h1B,
                                             hx, cstate, flags + 64 * FLG_STRIDE, cb, S);
    }

    heads_kernel<<<(NROWS * 10 + 255) / 256, 256, 0, stream>>>(
        h1B, Wp, bp, Wbu, bbu, W3, b3, W8, b8, Wa, ba, Wpp, bpp, out);
}

// Round 10
// 7715.400 us; speedup vs baseline: 9.4441x; 2.6610x over previous
//
#include <hip/hip_runtime.h>
#include <stdint.h>

// BiRNN: 2-layer BiLSTM (U=256) + heads. B=32, T=2048, F=64.
// R10: strip cache-maintenance from the per-step protocol. All hx/flag
// accesses are relaxed agent-scope atomics (LLC-direct, bypass L1/L2), so:
//  - consumer: poll flag relaxed, NO acquire (no L2 invalidate per step);
//  - producer: inline-asm s_waitcnt vmcnt(0) (+memory clobber) then relaxed
//    flag store, NO release (no L2 writeback per step).
// Ordering argument: data stores drained to LLC before flag store issues;
// consumer's data loads issue after its poll load returns (in-order wave
// issue + control dependency); all ops meet at the same LLC point.
// Everything else identical to the passing R9 kernel (absmax 3.9e-3).

#define T_SEQ 2048
#define BATCH 32
#define NROWS 65536   // B*T
#define NG 1024       // 4*U
#define FLG_STRIDE 32 // ints per chain (128 B)

typedef __attribute__((ext_vector_type(8))) short short8;
typedef __attribute__((ext_vector_type(4))) float f32x4;
typedef __attribute__((ext_vector_type(2))) float f32x2;

__device__ __forceinline__ ushort f32_to_bf16(float f) {
    uint32_t u = __float_as_uint(f);
    u = u + 0x7FFFu + ((u >> 16) & 1u);   // RNE
    return (ushort)(u >> 16);
}
__device__ __forceinline__ float bf16_to_f32(ushort h) {
    return __uint_as_float(((uint32_t)h) << 16);
}
__device__ __forceinline__ uint64_t split_pack4(f32x4 v, uint64_t& lo64) {
    ushort h0 = f32_to_bf16(v[0]), h1 = f32_to_bf16(v[1]);
    ushort h2 = f32_to_bf16(v[2]), h3 = f32_to_bf16(v[3]);
    ushort l0 = f32_to_bf16(v[0] - bf16_to_f32(h0));
    ushort l1 = f32_to_bf16(v[1] - bf16_to_f32(h1));
    ushort l2 = f32_to_bf16(v[2] - bf16_to_f32(h2));
    ushort l3 = f32_to_bf16(v[3] - bf16_to_f32(h3));
    lo64 = (uint64_t)l0 | ((uint64_t)l1 << 16) | ((uint64_t)l2 << 32) | ((uint64_t)l3 << 48);
    return (uint64_t)h0 | ((uint64_t)h1 << 16) | ((uint64_t)h2 << 32) | ((uint64_t)h3 << 48);
}

__global__ void init_flags_kernel(int* __restrict__ flags, int n) {
    int i = blockIdx.x * 256 + threadIdx.x;
    if (i < n) flags[i] = 0;
}

// Chunked split-GEMM: Cc[b*S+loc][:] = A[row_g][:] @ Bw + bias (all f32 I/O).
__global__ __launch_bounds__(256) void gemm_split_kernel(
    const float* __restrict__ A, int K,
    const float* __restrict__ Bw, const float* __restrict__ bias,
    float* __restrict__ Cc, int cb, int lsS, int dir)
{
    __shared__ __align__(16) ushort Ash[128 * 36];
    __shared__ __align__(16) ushort Asl[128 * 36];
    __shared__ __align__(16) ushort Bsh[128 * 36];
    __shared__ __align__(16) ushort Bsl[128 * 36];
    const int Smask = (1 << lsS) - 1;
    int t = threadIdx.x;
    int n0 = blockIdx.x * 128;
    int m0 = blockIdx.y * 128;
    int lane = t & 63, wv = t >> 6;
    int wr = wv >> 1, wc = wv & 1;
    int fr = lane & 15, fq = lane >> 4;

    f32x4 acc[4][4];
#pragma unroll
    for (int i = 0; i < 4; i++)
#pragma unroll
        for (int j = 0; j < 4; j++) acc[i][j] = (f32x4)(0.0f);

    int arow = t >> 1, ahalf = t & 1;
    int bc = t & 127, bkh = t >> 7;

    int loc_all = m0 + arow;
    int b = loc_all >> lsS;
    int loc = loc_all & Smask;
    int row_g = b * T_SEQ + (dir ? (T_SEQ - 1 - cb - loc) : (cb + loc));

    for (int k0 = 0; k0 < K; k0 += 32) {
        {   // stage A tile 128x32: 16 f32 per thread, split to hi/lo
            const float* s = A + (size_t)row_g * K + k0 + ahalf * 16;
            uint64_t* dh = (uint64_t*)&Ash[arow * 36 + ahalf * 16];
            uint64_t* dl = (uint64_t*)&Asl[arow * 36 + ahalf * 16];
#pragma unroll
            for (int g = 0; g < 4; g++) {
                f32x4 v = ((const f32x4*)s)[g];
                uint64_t lo64;
                uint64_t hi64 = split_pack4(v, lo64);
                dh[g] = hi64; dl[g] = lo64;
            }
        }
        {   // stage B tile 32x128 transposed -> [c][k], split to hi/lo
            float bv[16];
#pragma unroll
            for (int i = 0; i < 16; i++)
                bv[i] = Bw[(size_t)(k0 + bkh * 16 + i) * NG + n0 + bc];
            uint64_t* dh = (uint64_t*)&Bsh[bc * 36 + bkh * 16];
            uint64_t* dl = (uint64_t*)&Bsl[bc * 36 + bkh * 16];
#pragma unroll
            for (int g = 0; g < 4; g++) {
                f32x4 v = { bv[4 * g], bv[4 * g + 1], bv[4 * g + 2], bv[4 * g + 3] };
                uint64_t lo64;
                uint64_t hi64 = split_pack4(v, lo64);
                dh[g] = hi64; dl[g] = lo64;
            }
        }
        __syncthreads();
        union FU { uint64_t u[2]; short8 v; };
        FU bh[4], bl[4];
#pragma unroll
        for (int n = 0; n < 4; n++) {
            int boff = (wc * 64 + n * 16 + fr) * 36 + fq * 8;
            bh[n].u[0] = ((const uint64_t*)&Bsh[boff])[0];
            bh[n].u[1] = ((const uint64_t*)&Bsh[boff])[1];
            bl[n].u[0] = ((const uint64_t*)&Bsl[boff])[0];
            bl[n].u[1] = ((const uint64_t*)&Bsl[boff])[1];
        }
#pragma unroll
        for (int m = 0; m < 4; m++) {
            int aoff = (wr * 64 + m * 16 + fr) * 36 + fq * 8;
            FU ah, al;
            ah.u[0] = ((const uint64_t*)&Ash[aoff])[0];
            ah.u[1] = ((const uint64_t*)&Ash[aoff])[1];
            al.u[0] = ((const uint64_t*)&Asl[aoff])[0];
            al.u[1] = ((const uint64_t*)&Asl[aoff])[1];
#pragma unroll
            for (int n = 0; n < 4; n++) {
                acc[m][n] = __builtin_amdgcn_mfma_f32_16x16x32_bf16(ah.v, bh[n].v, acc[m][n], 0, 0, 0);
                acc[m][n] = __builtin_amdgcn_mfma_f32_16x16x32_bf16(ah.v, bl[n].v, acc[m][n], 0, 0, 0);
                acc[m][n] = __builtin_amdgcn_mfma_f32_16x16x32_bf16(al.v, bh[n].v, acc[m][n], 0, 0, 0);
            }
        }
        __syncthreads();
    }
#pragma unroll
    for (int m = 0; m < 4; m++)
#pragma unroll
        for (int n = 0; n < 4; n++) {
            int gcol = n0 + wc * 64 + n * 16 + fr;
            float bvv = bias[gcol];
#pragma unroll
            for (int i = 0; i < 4; i++) {
                int crow = m0 + wr * 64 + m * 16 + fq * 4 + i;
                Cc[(size_t)crow * NG + gcol] = acc[m][n][i] + bvv;
            }
        }
}

// One chunk of S steps for 2 LSTMs (fwd+bwd). 256 WGs.
// chain = wg&63, w = wg>>6 (chain's 4 WGs co-located per blockIdx%8 XCD rr).
__global__ __launch_bounds__(512, 2) void lstm_kernel(
    const float* __restrict__ Uf, const float* __restrict__ Ub,
    const float* __restrict__ xWcf, const float* __restrict__ xWcb,  // [B][S][NG] f32
    const int* __restrict__ mask,
    float* __restrict__ houtF,             // [NROWS][512] f32, +dir*256 (or null)
    ushort* __restrict__ houtB,            // [NROWS][512] bf16, +dir*256 (or null)
    float* __restrict__ hx,                // [64][2][256]: publish j at parity (j-1)&1
    float* __restrict__ cstate,            // [64][256]
    int* __restrict__ flags,               // [64][FLG_STRIDE]: publish count
    int cb, int S)
{
    int wg = blockIdx.x;
    int chain = wg & 63;
    int w = wg >> 6;
    int dir = chain >> 5;
    int b = chain & 31;
    const float* U = dir ? Ub : Uf;
    const float* xWc = dir ? xWcb : xWcf;

    int t = threadIdx.x;
    __shared__ __align__(16) float hbuf[256];
    __shared__ __align__(16) float pbuf[4 * 256];
    __shared__ int mbuf[2048];

    int kchunk = t >> 7;
    int cg = t & 127;
    int q = cg >> 5;
    int jj0 = 2 * (cg & 31);
    int col0 = q * 256 + w * 64 + jj0;

    // U slice in registers: 64 k x 2 cols = 128 regs
    f32x2 Ur[64];
    {
        const float* Up = U + (size_t)(kchunk * 64) * NG + col0;
#pragma unroll
        for (int i = 0; i < 64; i++) Ur[i] = *(const f32x2*)(Up + (size_t)i * NG);
    }
    float* hxc = hx + chain * 512;
    int* flg = flags + chain * FLG_STRIDE;
    int j = t & 63;
    int gj = w * 64 + j;
    int owner = t >> 6;

    // preload this chunk's mask into LDS
    for (int nl = t; nl < S; nl += 512) {
        int tp = dir ? (T_SEQ - 1 - (cb + nl)) : (cb + nl);
        mbuf[nl] = mask[b * T_SEQ + tp];
    }
    // publish count (all flags equal at kernel boundary)
    int kc = __hip_atomic_load(&flg[w], __ATOMIC_RELAXED, __HIP_MEMORY_SCOPE_AGENT);
    // restore hbuf = publish kc (complete at kernel boundary), zeros if none
    if (t < 256)
        hbuf[t] = (kc > 0)
            ? __hip_atomic_load(&hxc[((kc - 1) & 1) * 256 + t], __ATOMIC_RELAXED, __HIP_MEMORY_SCOPE_AGENT)
            : 0.0f;
    float creg = 0.0f, hreg = 0.0f;
    if (t < 64) {
        if (cb != 0) creg = cstate[chain * 256 + gj];
        if (kc > 0)
            hreg = __hip_atomic_load(&hxc[((kc - 1) & 1) * 256 + gj], __ATOMIC_RELAXED, __HIP_MEMORY_SCOPE_AGENT);
    }
    __syncthreads();

    for (int nl = 0; nl < S; nl++) {
        int tp = dir ? (T_SEQ - 1 - (cb + nl)) : (cb + nl);
        size_t row_g = (size_t)b * T_SEQ + tp;
        int mval = mbuf[nl];                 // uniform across WG (and chain)
        if (mval == 1) {
            // hold step: h,c unchanged; just emit output. No exchange at all.
            if (t < 64) {
                size_t oidx = row_g * 512 + dir * 256 + gj;
                if (houtF) houtF[oidx] = hreg;
                else       houtB[oidx] = f32_to_bf16(hreg);
            }
            continue;
        }
        // ---- active step ----
        float xw0 = 0.f, xw1 = 0.f, xw2 = 0.f, xw3 = 0.f;
        if (t < 64) {
            const float* xr = xWc + ((size_t)b * S + nl) * NG;
            xw0 = xr[gj];
            xw1 = xr[256 + gj];
            xw2 = xr[512 + gj];
            xw3 = xr[768 + gj];
        }
        // gather peers' publish kc: relaxed poll (lane 0), NO acquire — all
        // participating accesses are LLC-direct atomics; in-order issue after
        // the poll's control dependency gives the needed ordering.
        if (kc > 0 && t < 256 && owner != w) {
            if (j == 0) {
                while (__hip_atomic_load(&flg[owner], __ATOMIC_RELAXED, __HIP_MEMORY_SCOPE_AGENT) < kc)
                    __builtin_amdgcn_s_sleep(1);
            }
            hbuf[t] = __hip_atomic_load(&hxc[((kc - 1) & 1) * 256 + t], __ATOMIC_RELAXED, __HIP_MEMORY_SCOPE_AGENT);
        }
        __syncthreads();   // (C)
        // partial dot: 2 cols x 64 k, exact f32 FMA, U in registers
        float a0 = 0.0f, a1 = 0.0f;
        {
            const float* hb = &hbuf[kchunk * 64];
#pragma unroll
            for (int i = 0; i < 16; i++) {
                f32x4 h4 = *(const f32x4*)(hb + 4 * i);
#pragma unroll
                for (int j2 = 0; j2 < 4; j2++) {
                    a0 += h4[j2] * Ur[4 * i + j2][0];
                    a1 += h4[j2] * Ur[4 * i + j2][1];
                }
            }
        }
        {
            f32x2 pv = {a0, a1};
            *(f32x2*)&pbuf[kchunk * 256 + 2 * cg] = pv;
        }
        __syncthreads();   // (E)
        if (t < 64) {
            float zi = xw0 + pbuf[j]       + pbuf[256 + j]       + pbuf[512 + j]       + pbuf[768 + j];
            float zf = xw1 + pbuf[64 + j]  + pbuf[256 + 64 + j]  + pbuf[512 + 64 + j]  + pbuf[768 + 64 + j];
            float zg = xw2 + pbuf[128 + j] + pbuf[256 + 128 + j] + pbuf[512 + 128 + j] + pbuf[768 + 128 + j];
            float zo = xw3 + pbuf[192 + j] + pbuf[256 + 192 + j] + pbuf[512 + 192 + j] + pbuf[768 + 192 + j];
            float ig = 1.0f / (1.0f + expf(-zi));
            float fg = 1.0f / (1.0f + expf(-zf));
            float gg = tanhf(zg);
            float og = 1.0f / (1.0f + expf(-zo));
            float cn = fg * creg + ig * gg;
            float hn = og * tanhf(cn);
            creg = cn; hreg = hn;
            hbuf[gj] = hn;
            size_t oidx = row_g * 512 + dir * 256 + gj;
            if (houtF) houtF[oidx] = hn;
            else       houtB[oidx] = f32_to_bf16(hn);
            // publish kc+1 at parity kc&1 (relaxed store, LLC-direct)
            __hip_atomic_store(&hxc[(kc & 1) * 256 + gj], hn, __ATOMIC_RELAXED, __HIP_MEMORY_SCOPE_AGENT);
            if (t == 0) {
                // drain the wave's data stores to the LLC, then raise the flag.
                asm volatile("s_waitcnt vmcnt(0)" ::: "memory");
                __hip_atomic_store(&flg[w], kc + 1, __ATOMIC_RELAXED, __HIP_MEMORY_SCOPE_AGENT);
            }
        }
        kc++;   // uniform across WG
    }
    if (t < 64) cstate[chain * 256 + gj] = creg;
}

struct HP { const float* W; const float* bs; int nc; int lc; size_t off; };
__device__ __forceinline__ HP resolve_head(int j,
    const float* Wp, const float* bp, const float* Wbu, const float* bbu,
    const float* W3, const float* b3, const float* W8, const float* b8,
    const float* Wa, const float* ba, const float* Wpp, const float* bpp)
{
    HP h;
    if (j < 2)       { h.W = Wp;  h.bs = bp;  h.nc = 2; h.lc = j;      h.off = 0; }
    else if (j < 4)  { h.W = Wbu; h.bs = bbu; h.nc = 2; h.lc = j - 2;  h.off = (size_t)NROWS * 2; }
    else if (j < 7)  { h.W = W3;  h.bs = b3;  h.nc = 3; h.lc = j - 4;  h.off = (size_t)NROWS * 4; }
    else if (j < 15) { h.W = W8;  h.bs = b8;  h.nc = 8; h.lc = j - 7;  h.off = (size_t)NROWS * 7; }
    else if (j < 16) { h.W = Wa;  h.bs = ba;  h.nc = 1; h.lc = 0;      h.off = (size_t)NROWS * 15; }
    else             { h.W = Wpp; h.bs = bpp; h.nc = 4; h.lc = j - 16; h.off = (size_t)NROWS * 16; }
    return h;
}

__global__ __launch_bounds__(256) void heads_kernel(
    const ushort* __restrict__ h1,   // [NROWS][512] bf16
    const float* __restrict__ Wp, const float* __restrict__ bp,
    const float* __restrict__ Wbu, const float* __restrict__ bbu,
    const float* __restrict__ W3, const float* __restrict__ b3,
    const float* __restrict__ W8, const float* __restrict__ b8,
    const float* __restrict__ Wa, const float* __restrict__ ba,
    const float* __restrict__ Wpp, const float* __restrict__ bpp,
    float* __restrict__ out)
{
    int idx = blockIdx.x * 256 + threadIdx.x;
    if (idx >= NROWS * 10) return;
    int r = idx / 10;
    int pair = idx - r * 10;
    int j0 = 2 * pair;
    HP p0 = resolve_head(j0, Wp, bp, Wbu, bbu, W3, b3, W8, b8, Wa, ba, Wpp, bpp);
    HP p1 = resolve_head(j0 + 1, Wp, bp, Wbu, bbu, W3, b3, W8, b8, Wa, ba, Wpp, bpp);
    const ushort* hr = h1 + (size_t)r * 512;
    float s0 = 0.0f, s1 = 0.0f;
    for (int k = 0; k < 512; k += 8) {
        union { uint4 u4; ushort us[8]; } hu;
        hu.u4 = *(const uint4*)(hr + k);
#pragma unroll
        for (int u = 0; u < 8; u++) {
            float hv = fmaxf(bf16_to_f32(hu.us[u]), 0.0f);   // relu
            s0 += hv * p0.W[(k + u) * p0.nc + p0.lc];
            s1 += hv * p1.W[(k + u) * p1.nc + p1.lc];
        }
    }
    s0 += p0.bs[p0.lc];
    s1 += p1.bs[p1.lc];
    if (pair == 0) {   // ppi softmax over 2 logits
        float mx = fmaxf(s0, s1);
        float e0 = expf(s0 - mx), e1 = expf(s1 - mx);
        float inv = 1.0f / (e0 + e1);
        out[(size_t)r * 2]     = e0 * inv;
        out[(size_t)r * 2 + 1] = e1 * inv;
    } else {
        out[p0.off + (size_t)r * p0.nc + p0.lc] = s0;
        out[p1.off + (size_t)r * p1.nc + p1.lc] = s1;
    }
}

extern "C" void kernel_launch(void* const* d_in, const int* in_sizes, int n_in,
                              void* d_out, int out_size, void* d_ws, size_t ws_size,
                              hipStream_t stream) {
    const float* x    = (const float*)d_in[0];
    const int* xmask  = (const int*)d_in[1];
    const float* Wf0  = (const float*)d_in[3];
    const float* Uf0  = (const float*)d_in[4];
    const float* bf0  = (const float*)d_in[5];
    const float* Wb0  = (const float*)d_in[6];
    const float* Ub0  = (const float*)d_in[7];
    const float* bb0  = (const float*)d_in[8];
    const float* Wf1  = (const float*)d_in[9];
    const float* Uf1  = (const float*)d_in[10];
    const float* bf1  = (const float*)d_in[11];
    const float* Wb1  = (const float*)d_in[12];
    const float* Ub1  = (const float*)d_in[13];
    const float* bb1  = (const float*)d_in[14];
    const float* Wp   = (const float*)d_in[15]; const float* bp  = (const float*)d_in[16];
    const float* Wbu  = (const float*)d_in[17]; const float* bbu = (const float*)d_in[18];
    const float* W3   = (const float*)d_in[19]; const float* b3  = (const float*)d_in[20];
    const float* W8   = (const float*)d_in[21]; const float* b8  = (const float*)d_in[22];
    const float* Wa   = (const float*)d_in[23]; const float* ba  = (const float*)d_in[24];
    const float* Wpp  = (const float*)d_in[25]; const float* bpp = (const float*)d_in[26];
    float* out = (float*)d_out;

    char* ws = (char*)d_ws;
    size_t off = 0;
    auto take = [&](size_t bytes) -> void* {
        void* p = ws + off;
        off += (bytes + 255) & ~(size_t)255;
        return p;
    };
    int*    flags  = (int*)take((size_t)2 * 64 * FLG_STRIDE * 4);   // layer0 + layer1
    float*  hx     = (float*)take((size_t)64 * 2 * 256 * 4);
    float*  cstate = (float*)take((size_t)64 * 256 * 4);
    float*  h0F    = (float*)take((size_t)NROWS * 512 * 4);    // 134.2 MB (f32)
    ushort* h1B    = (ushort*)take((size_t)NROWS * 512 * 2);   // 67.1 MB (bf16)
    size_t fixed = off;

    // adaptive chunk: xW f32 chunk buffers cost S*262144 bytes (both dirs)
    int S = 8, lsS = 3;
    for (int cand = 11; cand >= 3; cand--) {
        if (fixed + (((size_t)1 << cand) * 262144) + 4096 <= ws_size) { S = 1 << cand; lsS = cand; break; }
    }
    float* xWcf = (float*)take((size_t)BATCH * S * NG * 4);
    float* xWcb = (float*)take((size_t)BATCH * S * NG * 4);
    int NC = T_SEQ / S;
    (void)in_sizes; (void)n_in; (void)out_size;

    init_flags_kernel<<<(2 * 64 * FLG_STRIDE + 255) / 256, 256, 0, stream>>>(flags, 2 * 64 * FLG_STRIDE);

    dim3 ggrid(NG / 128, (BATCH * S) / 128);
    // layer 0: A = x (f32, K=64), writes h0F (f32)
    for (int c = 0; c < NC; c++) {
        int cb = c * S;
        gemm_split_kernel<<<ggrid, 256, 0, stream>>>(x, 64, Wf0, bf0, xWcf, cb, lsS, 0);
        gemm_split_kernel<<<ggrid, 256, 0, stream>>>(x, 64, Wb0, bb0, xWcb, cb, lsS, 1);
        lstm_kernel<<<256, 512, 0, stream>>>(Uf0, Ub0, xWcf, xWcb, xmask, h0F, nullptr,
                                             hx, cstate, flags, cb, S);
    }
    // layer 1: A = h0F (f32, K=512, read-only), writes h1B (bf16)
    for (int c = 0; c < NC; c++) {
        int cb = c * S;
        gemm_split_kernel<<<ggrid, 256, 0, stream>>>(h0F, 512, Wf1, bf1, xWcf, cb, lsS, 0);
        gemm_split_kernel<<<ggrid, 256, 0, stream>>>(h0F, 512, Wb1, bb1, xWcb, cb, lsS, 1);
        lstm_kernel<<<256, 512, 0, stream>>>(Uf1, Ub1, xWcf, xWcb, xmask, nullptr, h1B,
                                             hx, cstate, flags + 64 * FLG_STRIDE, cb, S);
    }

    heads_kernel<<<(NROWS * 10 + 255) / 256, 256, 0, stream>>>(
        h1B, Wp, bp, Wbu, bbu, W3, b3, W8, b8, Wa, ba, Wpp, bpp, out);
}

// Round 11
// 5613.123 us; speedup vs baseline: 12.9812x; 1.3745x over previous
//
#include <hip/hip_runtime.h>
#include <stdint.h>

// BiRNN: 2-layer BiLSTM (U=256) + heads. B=32, T=2048, F=64.
// R11: (1) packed {h,cnt} 8-byte atomic exchange — no flag, no vmcnt drain,
// no separate gather RT; consumer's successful poll carries the data.
// Layer-1 has its own hxp region (cnt namespaces must not collide).
// (2) heads: wave-per-row shuffle-reduce, weights register-resident.
// Recurrence math identical to passing R6-R10 (absmax 3.9e-3).

#define T_SEQ 2048
#define BATCH 32
#define NROWS 65536   // B*T
#define NG 1024       // 4*U
#define FLG_STRIDE 32 // ints per chain (128 B)

typedef __attribute__((ext_vector_type(8))) short short8;
typedef __attribute__((ext_vector_type(4))) float f32x4;
typedef __attribute__((ext_vector_type(2))) float f32x2;

__device__ __forceinline__ ushort f32_to_bf16(float f) {
    uint32_t u = __float_as_uint(f);
    u = u + 0x7FFFu + ((u >> 16) & 1u);   // RNE
    return (ushort)(u >> 16);
}
__device__ __forceinline__ float bf16_to_f32(ushort h) {
    return __uint_as_float(((uint32_t)h) << 16);
}
__device__ __forceinline__ uint64_t split_pack4(f32x4 v, uint64_t& lo64) {
    ushort h0 = f32_to_bf16(v[0]), h1 = f32_to_bf16(v[1]);
    ushort h2 = f32_to_bf16(v[2]), h3 = f32_to_bf16(v[3]);
    ushort l0 = f32_to_bf16(v[0] - bf16_to_f32(h0));
    ushort l1 = f32_to_bf16(v[1] - bf16_to_f32(h1));
    ushort l2 = f32_to_bf16(v[2] - bf16_to_f32(h2));
    ushort l3 = f32_to_bf16(v[3] - bf16_to_f32(h3));
    lo64 = (uint64_t)l0 | ((uint64_t)l1 << 16) | ((uint64_t)l2 << 32) | ((uint64_t)l3 << 48);
    return (uint64_t)h0 | ((uint64_t)h1 << 16) | ((uint64_t)h2 << 32) | ((uint64_t)h3 << 48);
}

// zero flags (both layers) and hxp (both layers; poison 0xAA would false-pass the cnt gate)
__global__ void init_ctrl_kernel(int* __restrict__ flags, int nf,
                                 unsigned long long* __restrict__ hxp, int nh) {
    int i = blockIdx.x * 256 + threadIdx.x;
    if (i < nf) flags[i] = 0;
    if (i < nh) hxp[i] = 0ull;
}

// Chunked split-GEMM: Cc[b*S+loc][:] = A[row_g][:] @ Bw + bias (all f32 I/O).
__global__ __launch_bounds__(256) void gemm_split_kernel(
    const float* __restrict__ A, int K,
    const float* __restrict__ Bw, const float* __restrict__ bias,
    float* __restrict__ Cc, int cb, int lsS, int dir)
{
    __shared__ __align__(16) ushort Ash[128 * 36];
    __shared__ __align__(16) ushort Asl[128 * 36];
    __shared__ __align__(16) ushort Bsh[128 * 36];
    __shared__ __align__(16) ushort Bsl[128 * 36];
    const int Smask = (1 << lsS) - 1;
    int t = threadIdx.x;
    int n0 = blockIdx.x * 128;
    int m0 = blockIdx.y * 128;
    int lane = t & 63, wv = t >> 6;
    int wr = wv >> 1, wc = wv & 1;
    int fr = lane & 15, fq = lane >> 4;

    f32x4 acc[4][4];
#pragma unroll
    for (int i = 0; i < 4; i++)
#pragma unroll
        for (int j = 0; j < 4; j++) acc[i][j] = (f32x4)(0.0f);

    int arow = t >> 1, ahalf = t & 1;
    int bc = t & 127, bkh = t >> 7;

    int loc_all = m0 + arow;
    int b = loc_all >> lsS;
    int loc = loc_all & Smask;
    int row_g = b * T_SEQ + (dir ? (T_SEQ - 1 - cb - loc) : (cb + loc));

    for (int k0 = 0; k0 < K; k0 += 32) {
        {   // stage A tile 128x32: 16 f32 per thread, split to hi/lo
            const float* s = A + (size_t)row_g * K + k0 + ahalf * 16;
            uint64_t* dh = (uint64_t*)&Ash[arow * 36 + ahalf * 16];
            uint64_t* dl = (uint64_t*)&Asl[arow * 36 + ahalf * 16];
#pragma unroll
            for (int g = 0; g < 4; g++) {
                f32x4 v = ((const f32x4*)s)[g];
                uint64_t lo64;
                uint64_t hi64 = split_pack4(v, lo64);
                dh[g] = hi64; dl[g] = lo64;
            }
        }
        {   // stage B tile 32x128 transposed -> [c][k], split to hi/lo
            float bv[16];
#pragma unroll
            for (int i = 0; i < 16; i++)
                bv[i] = Bw[(size_t)(k0 + bkh * 16 + i) * NG + n0 + bc];
            uint64_t* dh = (uint64_t*)&Bsh[bc * 36 + bkh * 16];
            uint64_t* dl = (uint64_t*)&Bsl[bc * 36 + bkh * 16];
#pragma unroll
            for (int g = 0; g < 4; g++) {
                f32x4 v = { bv[4 * g], bv[4 * g + 1], bv[4 * g + 2], bv[4 * g + 3] };
                uint64_t lo64;
                uint64_t hi64 = split_pack4(v, lo64);
                dh[g] = hi64; dl[g] = lo64;
            }
        }
        __syncthreads();
        union FU { uint64_t u[2]; short8 v; };
        FU bh[4], bl[4];
#pragma unroll
        for (int n = 0; n < 4; n++) {
            int boff = (wc * 64 + n * 16 + fr) * 36 + fq * 8;
            bh[n].u[0] = ((const uint64_t*)&Bsh[boff])[0];
            bh[n].u[1] = ((const uint64_t*)&Bsh[boff])[1];
            bl[n].u[0] = ((const uint64_t*)&Bsl[boff])[0];
            bl[n].u[1] = ((const uint64_t*)&Bsl[boff])[1];
        }
#pragma unroll
        for (int m = 0; m < 4; m++) {
            int aoff = (wr * 64 + m * 16 + fr) * 36 + fq * 8;
            FU ah, al;
            ah.u[0] = ((const uint64_t*)&Ash[aoff])[0];
            ah.u[1] = ((const uint64_t*)&Ash[aoff])[1];
            al.u[0] = ((const uint64_t*)&Asl[aoff])[0];
            al.u[1] = ((const uint64_t*)&Asl[aoff])[1];
#pragma unroll
            for (int n = 0; n < 4; n++) {
                acc[m][n] = __builtin_amdgcn_mfma_f32_16x16x32_bf16(ah.v, bh[n].v, acc[m][n], 0, 0, 0);
                acc[m][n] = __builtin_amdgcn_mfma_f32_16x16x32_bf16(ah.v, bl[n].v, acc[m][n], 0, 0, 0);
                acc[m][n] = __builtin_amdgcn_mfma_f32_16x16x32_bf16(al.v, bh[n].v, acc[m][n], 0, 0, 0);
            }
        }
        __syncthreads();
    }
#pragma unroll
    for (int m = 0; m < 4; m++)
#pragma unroll
        for (int n = 0; n < 4; n++) {
            int gcol = n0 + wc * 64 + n * 16 + fr;
            float bvv = bias[gcol];
#pragma unroll
            for (int i = 0; i < 4; i++) {
                int crow = m0 + wr * 64 + m * 16 + fq * 4 + i;
                Cc[(size_t)crow * NG + gcol] = acc[m][n][i] + bvv;
            }
        }
}

// One chunk of S steps for 2 LSTMs (fwd+bwd). 256 WGs.
// chain = wg&63, w = wg>>6 (chain's 4 WGs co-located per blockIdx%8 XCD rr).
// Exchange: packed {cnt:u32, h:f32} per lane. Publish p -> slot[(p-1)&1][gj]
// with cnt=p (one fire-and-forget 8B atomic store). Consumer for publish kc
// polls slot[(kc-1)&1][t] until cnt >= kc; the load carries h.
__global__ __launch_bounds__(512, 2) void lstm_kernel(
    const float* __restrict__ Uf, const float* __restrict__ Ub,
    const float* __restrict__ xWcf, const float* __restrict__ xWcb,  // [B][S][NG] f32
    const int* __restrict__ mask,
    float* __restrict__ houtF,             // [NROWS][512] f32, +dir*256 (or null)
    ushort* __restrict__ houtB,            // [NROWS][512] bf16, +dir*256 (or null)
    unsigned long long* __restrict__ hxp,  // [64][2][256] packed
    float* __restrict__ cstate,            // [64][256]
    int* __restrict__ flags,               // [64][FLG_STRIDE]: kc at chunk boundary
    int cb, int S)
{
    int wg = blockIdx.x;
    int chain = wg & 63;
    int w = wg >> 6;
    int dir = chain >> 5;
    int b = chain & 31;
    const float* U = dir ? Ub : Uf;
    const float* xWc = dir ? xWcb : xWcf;

    int t = threadIdx.x;
    __shared__ __align__(16) float hbuf[256];
    __shared__ __align__(16) float pbuf[4 * 256];
    __shared__ int mbuf[2048];

    int kchunk = t >> 7;
    int cg = t & 127;
    int q = cg >> 5;
    int jj0 = 2 * (cg & 31);
    int col0 = q * 256 + w * 64 + jj0;

    // U slice in registers: 64 k x 2 cols = 128 regs
    f32x2 Ur[64];
    {
        const float* Up = U + (size_t)(kchunk * 64) * NG + col0;
#pragma unroll
        for (int i = 0; i < 64; i++) Ur[i] = *(const f32x2*)(Up + (size_t)i * NG);
    }
    unsigned long long* hxpc = hxp + chain * 512;
    int* flg = flags + chain * FLG_STRIDE;
    int j = t & 63;
    int gj = w * 64 + j;
    int owner = t >> 6;

    // preload this chunk's mask into LDS
    for (int nl = t; nl < S; nl += 512) {
        int tp = dir ? (T_SEQ - 1 - (cb + nl)) : (cb + nl);
        mbuf[nl] = mask[b * T_SEQ + tp];
    }
    // publish count at chunk boundary (all WGs in lockstep; w=0 stored it)
    int kc = __hip_atomic_load(&flg[0], __ATOMIC_RELAXED, __HIP_MEMORY_SCOPE_AGENT);
    // restore hbuf = publish kc (complete at kernel boundary), zeros if none
    if (t < 256) {
        if (kc > 0) {
            unsigned long long pk = __hip_atomic_load(&hxpc[((kc - 1) & 1) * 256 + t],
                                                      __ATOMIC_RELAXED, __HIP_MEMORY_SCOPE_AGENT);
            hbuf[t] = __uint_as_float((uint32_t)pk);
        } else {
            hbuf[t] = 0.0f;
        }
    }
    float creg = 0.0f, hreg = 0.0f;
    if (t < 64) {
        if (cb != 0) creg = cstate[chain * 256 + gj];
        if (kc > 0) {
            unsigned long long pk = __hip_atomic_load(&hxpc[((kc - 1) & 1) * 256 + gj],
                                                      __ATOMIC_RELAXED, __HIP_MEMORY_SCOPE_AGENT);
            hreg = __uint_as_float((uint32_t)pk);
        }
    }
    __syncthreads();

    for (int nl = 0; nl < S; nl++) {
        int tp = dir ? (T_SEQ - 1 - (cb + nl)) : (cb + nl);
        size_t row_g = (size_t)b * T_SEQ + tp;
        int mval = mbuf[nl];                 // uniform across WG (and chain)
        if (mval == 1) {
            // hold step: h,c unchanged; just emit output. No exchange at all.
            if (t < 64) {
                size_t oidx = row_g * 512 + dir * 256 + gj;
                if (houtF) houtF[oidx] = hreg;
                else       houtB[oidx] = f32_to_bf16(hreg);
            }
            continue;
        }
        // ---- active step ----
        float xw0 = 0.f, xw1 = 0.f, xw2 = 0.f, xw3 = 0.f;
        if (t < 64) {
            const float* xr = xWc + ((size_t)b * S + nl) * NG;
            xw0 = xr[gj];
            xw1 = xr[256 + gj];
            xw2 = xr[512 + gj];
            xw3 = xr[768 + gj];
        }
        // gather peers' publish kc: each lane polls its own packed slot;
        // the successful poll load carries the h value.
        if (kc > 0 && t < 256 && owner != w) {
            unsigned long long pk;
            for (;;) {
                pk = __hip_atomic_load(&hxpc[((kc - 1) & 1) * 256 + t],
                                       __ATOMIC_RELAXED, __HIP_MEMORY_SCOPE_AGENT);
                if ((uint32_t)(pk >> 32) >= (uint32_t)kc) break;
                __builtin_amdgcn_s_sleep(1);
            }
            hbuf[t] = __uint_as_float((uint32_t)pk);
        }
        __syncthreads();   // (C)
        // partial dot: 2 cols x 64 k, exact f32 FMA, U in registers
        float a0 = 0.0f, a1 = 0.0f;
        {
            const float* hb = &hbuf[kchunk * 64];
#pragma unroll
            for (int i = 0; i < 16; i++) {
                f32x4 h4 = *(const f32x4*)(hb + 4 * i);
#pragma unroll
                for (int j2 = 0; j2 < 4; j2++) {
                    a0 += h4[j2] * Ur[4 * i + j2][0];
                    a1 += h4[j2] * Ur[4 * i + j2][1];
                }
            }
        }
        {
            f32x2 pv = {a0, a1};
            *(f32x2*)&pbuf[kchunk * 256 + 2 * cg] = pv;
        }
        __syncthreads();   // (E)
        if (t < 64) {
            float zi = xw0 + pbuf[j]       + pbuf[256 + j]       + pbuf[512 + j]       + pbuf[768 + j];
            float zf = xw1 + pbuf[64 + j]  + pbuf[256 + 64 + j]  + pbuf[512 + 64 + j]  + pbuf[768 + 64 + j];
            float zg = xw2 + pbuf[128 + j] + pbuf[256 + 128 + j] + pbuf[512 + 128 + j] + pbuf[768 + 128 + j];
            float zo = xw3 + pbuf[192 + j] + pbuf[256 + 192 + j] + pbuf[512 + 192 + j] + pbuf[768 + 192 + j];
            float ig = 1.0f / (1.0f + expf(-zi));
            float fg = 1.0f / (1.0f + expf(-zf));
            float gg = tanhf(zg);
            float og = 1.0f / (1.0f + expf(-zo));
            float cn = fg * creg + ig * gg;
            float hn = og * tanhf(cn);
            creg = cn; hreg = hn;
            hbuf[gj] = hn;
            // publish kc+1 at slot[kc&1]: one fire-and-forget packed store.
            unsigned long long pk = ((unsigned long long)(uint32_t)(kc + 1) << 32)
                                  | (unsigned long long)(uint32_t)__float_as_uint(hn);
            __hip_atomic_store(&hxpc[(kc & 1) * 256 + gj], pk,
                               __ATOMIC_RELAXED, __HIP_MEMORY_SCOPE_AGENT);
            size_t oidx = row_g * 512 + dir * 256 + gj;
            if (houtF) houtF[oidx] = hn;
            else       houtB[oidx] = f32_to_bf16(hn);
        }
        kc++;   // uniform across WG
    }
    if (t < 64) cstate[chain * 256 + gj] = creg;
    if (w == 0 && t == 0)
        __hip_atomic_store(&flg[0], kc, __ATOMIC_RELAXED, __HIP_MEMORY_SCOPE_AGENT);
}

// heads: one wave per row; 64 lanes x 8 bf16 coalesced; 20 head-weights
// register-resident; butterfly shuffle reduce; lanes 0..19 scatter outputs.
__global__ __launch_bounds__(256, 2) void heads_kernel(
    const ushort* __restrict__ h1,   // [NROWS][512] bf16
    const float* __restrict__ Wp, const float* __restrict__ bp,
    const float* __restrict__ Wbu, const float* __restrict__ bbu,
    const float* __restrict__ W3, const float* __restrict__ b3,
    const float* __restrict__ W8, const float* __restrict__ b8,
    const float* __restrict__ Wa, const float* __restrict__ ba,
    const float* __restrict__ Wpp, const float* __restrict__ bpp,
    float* __restrict__ out)
{
    int gwv = (blockIdx.x * 256 + threadIdx.x) >> 6;
    int nwv = (gridDim.x * 256) >> 6;
    int lane = threadIdx.x & 63;
    int k0 = lane * 8;

    // weights: wr_[u][c], c = [Wp0,Wp1,Wbu0,Wbu1,W3x3,W8x8,Wa,Wppx4]
    float wr_[8][20];
#pragma unroll
    for (int u = 0; u < 8; u++) {
        int k = k0 + u;
        wr_[u][0]  = Wp[k * 2];      wr_[u][1]  = Wp[k * 2 + 1];
        wr_[u][2]  = Wbu[k * 2];     wr_[u][3]  = Wbu[k * 2 + 1];
        wr_[u][4]  = W3[k * 3];      wr_[u][5]  = W3[k * 3 + 1];  wr_[u][6] = W3[k * 3 + 2];
#pragma unroll
        for (int c = 0; c < 8; c++) wr_[u][7 + c] = W8[k * 8 + c];
        wr_[u][15] = Wa[k];
#pragma unroll
        for (int c = 0; c < 4; c++) wr_[u][16 + c] = Wpp[k * 4 + c];
    }
    // per-lane bias + output offset for lanes 0..19
    float myb = 0.0f;
    size_t ooff = 0;
    if (lane < 2)        { myb = bp[lane];        ooff = 0 + lane; }                      // stride 2
    else if (lane < 4)   { myb = bbu[lane - 2];   ooff = (size_t)NROWS * 2 + (lane - 2); }
    else if (lane < 7)   { myb = b3[lane - 4];    ooff = (size_t)NROWS * 4 + (lane - 4); }
    else if (lane < 15)  { myb = b8[lane - 7];    ooff = (size_t)NROWS * 7 + (lane - 7); }
    else if (lane < 16)  { myb = ba[0];           ooff = (size_t)NROWS * 15; }
    else if (lane < 20)  { myb = bpp[lane - 16];  ooff = (size_t)NROWS * 16 + (lane - 16); }
    float bp0 = bp[0], bp1 = bp[1];
    int stride = (lane < 2) ? 2 : (lane < 4) ? 2 : (lane < 7) ? 3 : (lane < 15) ? 8 : (lane < 16) ? 1 : 4;

    for (int r = gwv; r < NROWS; r += nwv) {
        union { uint4 u4; ushort us[8]; } hu;
        hu.u4 = *(const uint4*)(h1 + (size_t)r * 512 + k0);
        float acc[20];
#pragma unroll
        for (int c = 0; c < 20; c++) acc[c] = 0.0f;
#pragma unroll
        for (int u = 0; u < 8; u++) {
            float hv = fmaxf(bf16_to_f32(hu.us[u]), 0.0f);
#pragma unroll
            for (int c = 0; c < 20; c++) acc[c] += hv * wr_[u][c];
        }
#pragma unroll
        for (int off = 32; off >= 1; off >>= 1)
#pragma unroll
            for (int c = 0; c < 20; c++) acc[c] += __shfl_xor(acc[c], off);
        if (lane < 20) {
            float v = acc[lane] + myb;
            if (lane < 2) {   // ppi softmax over the 2 logits
                float s0 = acc[0] + bp0, s1 = acc[1] + bp1;
                float mx = fmaxf(s0, s1);
                float e0 = expf(s0 - mx), e1 = expf(s1 - mx);
                v = ((lane == 0) ? e0 : e1) / (e0 + e1);
            }
            out[ooff + (size_t)r * stride] = v;
        }
    }
}

extern "C" void kernel_launch(void* const* d_in, const int* in_sizes, int n_in,
                              void* d_out, int out_size, void* d_ws, size_t ws_size,
                              hipStream_t stream) {
    const float* x    = (const float*)d_in[0];
    const int* xmask  = (const int*)d_in[1];
    const float* Wf0  = (const float*)d_in[3];
    const float* Uf0  = (const float*)d_in[4];
    const float* bf0  = (const float*)d_in[5];
    const float* Wb0  = (const float*)d_in[6];
    const float* Ub0  = (const float*)d_in[7];
    const float* bb0  = (const float*)d_in[8];
    const float* Wf1  = (const float*)d_in[9];
    const float* Uf1  = (const float*)d_in[10];
    const float* bf1  = (const float*)d_in[11];
    const float* Wb1  = (const float*)d_in[12];
    const float* Ub1  = (const float*)d_in[13];
    const float* bb1  = (const float*)d_in[14];
    const float* Wp   = (const float*)d_in[15]; const float* bp  = (const float*)d_in[16];
    const float* Wbu  = (const float*)d_in[17]; const float* bbu = (const float*)d_in[18];
    const float* W3   = (const float*)d_in[19]; const float* b3  = (const float*)d_in[20];
    const float* W8   = (const float*)d_in[21]; const float* b8  = (const float*)d_in[22];
    const float* Wa   = (const float*)d_in[23]; const float* ba  = (const float*)d_in[24];
    const float* Wpp  = (const float*)d_in[25]; const float* bpp = (const float*)d_in[26];
    float* out = (float*)d_out;

    char* ws = (char*)d_ws;
    size_t off = 0;
    auto take = [&](size_t bytes) -> void* {
        void* p = ws + off;
        off += (bytes + 255) & ~(size_t)255;
        return p;
    };
    int* flags = (int*)take((size_t)2 * 64 * FLG_STRIDE * 4);              // layer0 + layer1
    unsigned long long* hxp = (unsigned long long*)take((size_t)2 * 64 * 2 * 256 * 8);  // 512 KB
    float*  cstate = (float*)take((size_t)64 * 256 * 4);
    float*  h0F    = (float*)take((size_t)NROWS * 512 * 4);    // 134.2 MB (f32)
    ushort* h1B    = (ushort*)take((size_t)NROWS * 512 * 2);   // 67.1 MB (bf16)
    size_t fixed = off;

    // adaptive chunk: xW f32 chunk buffers cost S*262144 bytes (both dirs)
    int S = 8, lsS = 3;
    for (int cand = 11; cand >= 3; cand--) {
        if (fixed + (((size_t)1 << cand) * 262144) + 4096 <= ws_size) { S = 1 << cand; lsS = cand; break; }
    }
    float* xWcf = (float*)take((size_t)BATCH * S * NG * 4);
    float* xWcb = (float*)take((size_t)BATCH * S * NG * 4);
    int NC = T_SEQ / S;
    (void)in_sizes; (void)n_in; (void)out_size;

    int nf = 2 * 64 * FLG_STRIDE;
    int nh = 2 * 64 * 2 * 256;
    int ninit = nh > nf ? nh : nf;
    init_ctrl_kernel<<<(ninit + 255) / 256, 256, 0, stream>>>(flags, nf, hxp, nh);

    dim3 ggrid(NG / 128, (BATCH * S) / 128);
    // layer 0: A = x (f32, K=64), writes h0F (f32)
    for (int c = 0; c < NC; c++) {
        int cb = c * S;
        gemm_split_kernel<<<ggrid, 256, 0, stream>>>(x, 64, Wf0, bf0, xWcf, cb, lsS, 0);
        gemm_split_kernel<<<ggrid, 256, 0, stream>>>(x, 64, Wb0, bb0, xWcb, cb, lsS, 1);
        lstm_kernel<<<256, 512, 0, stream>>>(Uf0, Ub0, xWcf, xWcb, xmask, h0F, nullptr,
                                             hxp, cstate, flags, cb, S);
    }
    // layer 1: A = h0F (f32, K=512, read-only), writes h1B (bf16); own hxp region
    for (int c = 0; c < NC; c++) {
        int cb = c * S;
        gemm_split_kernel<<<ggrid, 256, 0, stream>>>(h0F, 512, Wf1, bf1, xWcf, cb, lsS, 0);
        gemm_split_kernel<<<ggrid, 256, 0, stream>>>(h0F, 512, Wb1, bb1, xWcb, cb, lsS, 1);
        lstm_kernel<<<256, 512, 0, stream>>>(Uf1, Ub1, xWcf, xWcb, xmask, nullptr, h1B,
                                             hxp + (size_t)64 * 512, cstate, flags + 64 * FLG_STRIDE, cb, S);
    }

    heads_kernel<<<2048, 256, 0, stream>>>(
        h1B, Wp, bp, Wbu, bbu, W3, b3, W8, b8, Wa, ba, Wpp, bpp, out);
}